// Round 6
// baseline (299.294 us; speedup 1.0000x reference)
//
#include <hip/hip_runtime.h>
#include <math.h>

#define NN 50000      // nodes
#define NG 500        // graphs
#define CC 10
#define NBS 196       // cdiv(NN,256) scan blocks

static inline int cdiv(int a, int b) { return (a + b - 1) / b; }

__device__ inline unsigned bf16rne(float f) {
    unsigned u = __float_as_uint(f);
    return (u + 0x7fffu + ((u >> 16) & 1u)) >> 16;
}
__device__ inline unsigned pack2bf(float a, float b) {
    return bf16rne(a) | (bf16rne(b) << 16);
}

// ---------------- CSR build ----------------
__global__ void zero_int_kernel(int* __restrict__ a, int* __restrict__ b) {
    int i = blockIdx.x * 256 + threadIdx.x;
    if (i < NN) { a[i] = 0; b[i] = 0; }
}

__global__ void count_kernel(const int* __restrict__ dst, int* __restrict__ cnt, int nedges) {
    int e = blockIdx.x * 256 + threadIdx.x;
    if (e < nedges) atomicAdd(&cnt[dst[e]], 1);
}

__global__ void dinv_kernel(const int* __restrict__ cnt, float* __restrict__ dinv) {
    int n = blockIdx.x * 256 + threadIdx.x;
    if (n < NN) dinv[n] = rsqrtf((float)cnt[n] + 1.0f);  // +1 self-loop
}

__global__ void scan_block_kernel(const int* __restrict__ cnt, int* __restrict__ ptr, int* __restrict__ bsum) {
    __shared__ int s[256];
    int b = blockIdx.x, t = threadIdx.x;
    int i = b * 256 + t;
    int v = (i < NN) ? cnt[i] : 0;
    s[t] = v; __syncthreads();
    for (int off = 1; off < 256; off <<= 1) {
        int x = (t >= off) ? s[t - off] : 0; __syncthreads();
        s[t] += x; __syncthreads();
    }
    if (i < NN) ptr[i] = s[t] - v;
    if (t == 255) bsum[b] = s[255];
}

__global__ void scan_tops_kernel(int* __restrict__ bsum) {
    __shared__ int s[256];
    int t = threadIdx.x;
    int v = (t < NBS) ? bsum[t] : 0;
    s[t] = v; __syncthreads();
    for (int off = 1; off < 256; off <<= 1) {
        int x = (t >= off) ? s[t - off] : 0; __syncthreads();
        s[t] += x; __syncthreads();
    }
    if (t < NBS) bsum[t] = s[t] - v;
}

__global__ void scan_add_kernel(int* __restrict__ ptr, const int* __restrict__ bsum) {
    int i = blockIdx.x * 256 + threadIdx.x;
    if (i < NN) ptr[i] += bsum[blockIdx.x];
}

__global__ void csr_fill_kernel(const int* __restrict__ src, const int* __restrict__ dst,
                                const int* __restrict__ ptr, int* __restrict__ fill,
                                int* __restrict__ csr_src, int nedges) {
    int e = blockIdx.x * 256 + threadIdx.x;
    if (e >= nedges) return;
    int d = dst[e];
    int pos = ptr[d] + atomicAdd(&fill[d], 1);
    csr_src[pos] = src[e];
}

// ---------------- register-tiled dense matmul: out = (relu?)(h) @ W [+bias] ----------------
// k-blocked float4 dual-operand loads: per 4-k block, 4+TM ds_read_b128 feed TM*16 FMAs.
template <int K, int OUT, int WCOLS, bool RELU_IN, bool RELU_OUT, bool BIAS, bool OUT_BF16>
__global__ __launch_bounds__(256) void mm_kernel(
    const float* __restrict__ h, int hstride,
    const float* __restrict__ w, const float* __restrict__ bias,
    float* __restrict__ out, int ostride)
{
    constexpr int KC = 64;
    constexpr int NCH = K / KC;
    constexpr int NCOL = OUT / 4;
    constexpr int NROW = 256 / NCOL;
    constexpr int TM = 64 / NROW;
    __shared__ float sW[KC * OUT];
    __shared__ float sX[64][KC + 4];
    int tid = threadIdx.x;
    int tx = tid % NCOL, ty = tid / NCOL;
    int base = blockIdx.x * 64;
    int r0 = ty * TM;

    float acc[TM][4];
    #pragma unroll
    for (int i = 0; i < TM; ++i) {
        #pragma unroll
        for (int j = 0; j < 4; ++j)
            acc[i][j] = BIAS ? ((tx * 4 + j < WCOLS) ? bias[tx * 4 + j] : 0.0f) : 0.0f;
    }

    for (int ch = 0; ch < NCH; ++ch) {
        int kc = ch * KC;
        if (ch) __syncthreads();
        if constexpr (WCOLS == OUT) {
            for (int i = tid * 4; i < KC * OUT; i += 1024)
                *reinterpret_cast<float4*>(&sW[i]) =
                    *reinterpret_cast<const float4*>(&w[kc * OUT + i]);
        } else {
            for (int i = tid; i < KC * OUT; i += 256) {
                int k = i / OUT, o = i % OUT;
                sW[i] = (o < WCOLS) ? w[(kc + k) * WCOLS + o] : 0.0f;
            }
        }
        for (int i = tid * 4; i < 64 * KC; i += 1024) {
            int r = i / KC, c = i % KC;
            int gn = base + r;
            float4 v = make_float4(0.f, 0.f, 0.f, 0.f);
            if (gn < NN)
                v = *reinterpret_cast<const float4*>(&h[(size_t)gn * hstride + kc + c]);
            if (RELU_IN) {
                v.x = fmaxf(v.x, 0.f); v.y = fmaxf(v.y, 0.f);
                v.z = fmaxf(v.z, 0.f); v.w = fmaxf(v.w, 0.f);
            }
            *reinterpret_cast<float4*>(&sX[r][c]) = v;
        }
        __syncthreads();
        #pragma unroll 2
        for (int kb = 0; kb < KC; kb += 4) {
            float4 wv0 = *reinterpret_cast<const float4*>(&sW[(kb + 0) * OUT + tx * 4]);
            float4 wv1 = *reinterpret_cast<const float4*>(&sW[(kb + 1) * OUT + tx * 4]);
            float4 wv2 = *reinterpret_cast<const float4*>(&sW[(kb + 2) * OUT + tx * 4]);
            float4 wv3 = *reinterpret_cast<const float4*>(&sW[(kb + 3) * OUT + tx * 4]);
            #pragma unroll
            for (int i = 0; i < TM; ++i) {
                float4 xv = *reinterpret_cast<const float4*>(&sX[r0 + i][kb]);
                acc[i][0] = fmaf(xv.x, wv0.x, acc[i][0]);
                acc[i][1] = fmaf(xv.x, wv0.y, acc[i][1]);
                acc[i][2] = fmaf(xv.x, wv0.z, acc[i][2]);
                acc[i][3] = fmaf(xv.x, wv0.w, acc[i][3]);
                acc[i][0] = fmaf(xv.y, wv1.x, acc[i][0]);
                acc[i][1] = fmaf(xv.y, wv1.y, acc[i][1]);
                acc[i][2] = fmaf(xv.y, wv1.z, acc[i][2]);
                acc[i][3] = fmaf(xv.y, wv1.w, acc[i][3]);
                acc[i][0] = fmaf(xv.z, wv2.x, acc[i][0]);
                acc[i][1] = fmaf(xv.z, wv2.y, acc[i][1]);
                acc[i][2] = fmaf(xv.z, wv2.z, acc[i][2]);
                acc[i][3] = fmaf(xv.z, wv2.w, acc[i][3]);
                acc[i][0] = fmaf(xv.w, wv3.x, acc[i][0]);
                acc[i][1] = fmaf(xv.w, wv3.y, acc[i][1]);
                acc[i][2] = fmaf(xv.w, wv3.z, acc[i][2]);
                acc[i][3] = fmaf(xv.w, wv3.w, acc[i][3]);
            }
        }
    }

    #pragma unroll
    for (int i = 0; i < TM; ++i) {
        int gn = base + r0 + i;
        if (gn >= NN) continue;
        float4 v;
        v.x = acc[i][0]; v.y = acc[i][1]; v.z = acc[i][2]; v.w = acc[i][3];
        if (RELU_OUT) {
            v.x = fmaxf(v.x, 0.f); v.y = fmaxf(v.y, 0.f);
            v.z = fmaxf(v.z, 0.f); v.w = fmaxf(v.w, 0.f);
        }
        if constexpr (OUT_BF16) {
            unsigned* orow = reinterpret_cast<unsigned*>(out) + (size_t)gn * (ostride >> 1) + tx * 2;
            uint2 pv;
            pv.x = pack2bf(v.x, v.y);
            pv.y = pack2bf(v.z, v.w);
            *reinterpret_cast<uint2*>(orow) = pv;
        } else {
            *reinterpret_cast<float4*>(&out[(size_t)gn * ostride + tx * 4]) = v;
        }
    }
}

// ---------------- CSR gather, 128 bf16 channels: one wave per node ----------------
__global__ __launch_bounds__(256) void gcn_gather128_bf16_kernel(
    const int* __restrict__ csr_src, const int* __restrict__ ptr, const int* __restrict__ cnt,
    const float* __restrict__ dinv, const unsigned* __restrict__ hw, const float* __restrict__ b,
    float* __restrict__ out)
{
    int tid = threadIdx.x;
    int n = blockIdx.x * 4 + (tid >> 6);
    if (n >= NN) return;
    int lane = tid & 63;
    float di = dinv[n];
    unsigned p0 = hw[(size_t)n * 64 + lane];
    float2 bb = *reinterpret_cast<const float2*>(b + lane * 2);
    float ax = bb.x + __uint_as_float(p0 << 16) * di * di;
    float ay = bb.y + __uint_as_float(p0 & 0xffff0000u) * di * di;
    int s0 = ptr[n], c = cnt[n];
    int i = 0;
    for (; i + 3 < c; i += 4) {
        int sa = csr_src[s0 + i + 0];
        int sb = csr_src[s0 + i + 1];
        int sc = csr_src[s0 + i + 2];
        int sd = csr_src[s0 + i + 3];
        float na = dinv[sa] * di, nb = dinv[sb] * di;
        float nc = dinv[sc] * di, nd = dinv[sd] * di;
        unsigned pa = hw[(size_t)sa * 64 + lane];
        unsigned pb = hw[(size_t)sb * 64 + lane];
        unsigned pc = hw[(size_t)sc * 64 + lane];
        unsigned pd = hw[(size_t)sd * 64 + lane];
        ax = fmaf(__uint_as_float(pa << 16), na, ax);
        ay = fmaf(__uint_as_float(pa & 0xffff0000u), na, ay);
        ax = fmaf(__uint_as_float(pb << 16), nb, ax);
        ay = fmaf(__uint_as_float(pb & 0xffff0000u), nb, ay);
        ax = fmaf(__uint_as_float(pc << 16), nc, ax);
        ay = fmaf(__uint_as_float(pc & 0xffff0000u), nc, ay);
        ax = fmaf(__uint_as_float(pd << 16), nd, ax);
        ay = fmaf(__uint_as_float(pd & 0xffff0000u), nd, ay);
    }
    for (; i < c; ++i) {
        int sa = csr_src[s0 + i];
        float na = dinv[sa] * di;
        unsigned pa = hw[(size_t)sa * 64 + lane];
        ax = fmaf(__uint_as_float(pa << 16), na, ax);
        ay = fmaf(__uint_as_float(pa & 0xffff0000u), na, ay);
    }
    float2 r; r.x = ax; r.y = ay;
    *reinterpret_cast<float2*>(out + (size_t)n * 128 + lane * 2) = r;
}

// ---------------- CSR gather, 10 channels (stride 16): 16 threads per node ----------------
__global__ void gcn_gather10_kernel(
    const int* __restrict__ csr_src, const int* __restrict__ ptr, const int* __restrict__ cnt,
    const float* __restrict__ dinv, const float* __restrict__ hw, const float* __restrict__ b,
    float* __restrict__ out)
{
    int idx = blockIdx.x * 256 + threadIdx.x;
    int n = idx >> 4;
    int ch = idx & 15;
    if (n >= NN || ch >= 10) return;
    float di = dinv[n];
    float acc = b[ch] + hw[n * 16 + ch] * di * di;
    int s0 = ptr[n], c = cnt[n];
    for (int i = 0; i < c; ++i) {
        int s = csr_src[s0 + i];
        acc += hw[s * 16 + ch] * (dinv[s] * di);
    }
    out[n * 16 + ch] = acc;
}

// ---------------- fused segmented pool + log_softmax (batch is sorted) ----------------
__global__ __launch_bounds__(256) void pool_ls_kernel(
    const float* __restrict__ h3, const int* __restrict__ batch, float* __restrict__ out)
{
    __shared__ int seg[2];
    __shared__ float red[16][17];
    int g = blockIdx.x;
    int t = threadIdx.x;
    if (t < 2) {
        int target = g + t;
        int lo = 0, hi = NN;
        while (lo < hi) {
            int mid = (lo + hi) >> 1;
            if (batch[mid] < target) lo = mid + 1; else hi = mid;
        }
        seg[t] = lo;
    }
    __syncthreads();
    int s = seg[0], e = seg[1];
    int ch = t & 15, nl = t >> 4;
    float acc = 0.0f;
    for (int n = s + nl; n < e; n += 16)
        if (ch < 10) acc += h3[(size_t)n * 16 + ch];
    red[nl][ch] = acc;
    __syncthreads();
    if (t < 16) {
        float ssum = 0.0f;
        #pragma unroll
        for (int i = 0; i < 16; ++i) ssum += red[i][t];
        red[0][t] = ssum;
    }
    __syncthreads();
    if (t == 0) {
        float c = fmaxf((float)(e - s), 1.0f);
        float v[10], m = -1e30f;
        #pragma unroll
        for (int i = 0; i < 10; ++i) { v[i] = red[0][i] / c; m = fmaxf(m, v[i]); }
        float ssum = 0.0f;
        #pragma unroll
        for (int i = 0; i < 10; ++i) ssum += expf(v[i] - m);
        float lse = m + logf(ssum);
        #pragma unroll
        for (int i = 0; i < 10; ++i) out[g * 10 + i] = v[i] - lse;
    }
}

extern "C" void kernel_launch(void* const* d_in, const int* in_sizes, int n_in,
                              void* d_out, int out_size, void* d_ws, size_t ws_size,
                              hipStream_t stream)
{
    const float* x      = (const float*)d_in[0];
    const int*   ei     = (const int*)d_in[1];
    const int*   batch  = (const int*)d_in[2];
    const float* emb_w1 = (const float*)d_in[3];
    const float* emb_b1 = (const float*)d_in[4];
    const float* emb_w2 = (const float*)d_in[5];
    const float* emb_b2 = (const float*)d_in[6];
    const float* w1     = (const float*)d_in[7];
    const float* b1     = (const float*)d_in[8];
    const float* w2     = (const float*)d_in[9];
    const float* b2     = (const float*)d_in[10];
    const float* w3     = (const float*)d_in[11];
    const float* b3     = (const float*)d_in[12];

    int E = in_sizes[1] / 2;
    const int* src = ei;
    const int* dst = ei + E;

    // workspace layout
    char* ws = (char*)d_ws;
    size_t off = 0;
    float* bufA   = (float*)(ws + off); off += (size_t)NN * 128 * 4;   // fp32 [NN,128]
    float* bufB   = (float*)(ws + off); off += (size_t)NN * 128 * 4;   // fp32; first half also emb tmp / layer3 out
    float* dinv   = (float*)(ws + off); off += (size_t)NN * 4;
    int*   cnt    = (int*)(ws + off);   off += (size_t)NN * 4;
    int*   ptr    = (int*)(ws + off);   off += (size_t)NN * 4;
    int*   fill   = (int*)(ws + off);   off += (size_t)NN * 4;
    int*   bsum   = (int*)(ws + off);   off += 256 * 4;
    int*   csrs   = (int*)(ws + off);   off += (size_t)E * 4;

    // bf16 hw buffer aliased into bufB's second half (NN*64 dwords = 12.8 MB)
    unsigned* hwb = (unsigned*)(bufB + (size_t)NN * 64);

    int mmgrid = cdiv(NN, 64);

    // ---- CSR build ----
    zero_int_kernel<<<cdiv(NN, 256), 256, 0, stream>>>(cnt, fill);
    count_kernel<<<cdiv(E, 256), 256, 0, stream>>>(dst, cnt, E);
    dinv_kernel<<<cdiv(NN, 256), 256, 0, stream>>>(cnt, dinv);
    scan_block_kernel<<<NBS, 256, 0, stream>>>(cnt, ptr, bsum);
    scan_tops_kernel<<<1, 256, 0, stream>>>(bsum);
    scan_add_kernel<<<NBS, 256, 0, stream>>>(ptr, bsum);
    csr_fill_kernel<<<cdiv(E, 256), 256, 0, stream>>>(src, dst, ptr, fill, csrs, E);

    // ---- embedder: x -> bufB(first half) -> bufA, both [NN,64] fp32 ----
    mm_kernel<64, 64, 64, false, true, true, false><<<mmgrid, 256, 0, stream>>>(x, 64, emb_w1, emb_b1, bufB, 64);
    mm_kernel<64, 64, 64, false, true, true, false><<<mmgrid, 256, 0, stream>>>(bufB, 64, emb_w2, emb_b2, bufA, 64);

    // ---- GCN layer 1: 64 -> 128, bf16 hw ----
    mm_kernel<64, 128, 128, false, false, false, true><<<mmgrid, 256, 0, stream>>>(bufA, 64, w1, nullptr, (float*)hwb, 128);
    gcn_gather128_bf16_kernel<<<cdiv(NN, 4), 256, 0, stream>>>(csrs, ptr, cnt, dinv, hwb, b1, bufA);

    // ---- GCN layer 2: 128 -> 128 (relu fused into X load), bf16 hw ----
    mm_kernel<128, 128, 128, true, false, false, true><<<mmgrid, 256, 0, stream>>>(bufA, 128, w2, nullptr, (float*)hwb, 128);
    gcn_gather128_bf16_kernel<<<cdiv(NN, 4), 256, 0, stream>>>(csrs, ptr, cnt, dinv, hwb, b2, bufA);

    // ---- GCN layer 3: 128 -> 10 fp32 (W padded to 16 cols) ----
    mm_kernel<128, 16, 10, true, false, false, false><<<mmgrid, 256, 0, stream>>>(bufA, 128, w3, nullptr, bufB, 16);
    gcn_gather10_kernel<<<cdiv(NN * 16, 256), 256, 0, stream>>>(csrs, ptr, cnt, dinv, bufB, b3, bufA);

    // ---- fused pooling + log_softmax (one block per graph) ----
    pool_ls_kernel<<<NG, 256, 0, stream>>>(bufA, batch, (float*)d_out);
}

// Round 7
// 288.839 us; speedup vs baseline: 1.0362x; 1.0362x over previous
//
#include <hip/hip_runtime.h>
#include <math.h>

#define NN 50000      // nodes
#define NG 500        // graphs
#define CC 10
#define NBS 196       // cdiv(NN,256) scan blocks

static inline int cdiv(int a, int b) { return (a + b - 1) / b; }

__device__ inline unsigned bf16rne(float f) {
    unsigned u = __float_as_uint(f);
    return (u + 0x7fffu + ((u >> 16) & 1u)) >> 16;
}
__device__ inline unsigned pack2bf(float a, float b) {
    return bf16rne(a) | (bf16rne(b) << 16);
}

// ---------------- CSR build ----------------
__global__ void zero_int_kernel(int* __restrict__ a) {
    int i = blockIdx.x * 256 + threadIdx.x;
    if (i < NN) a[i] = 0;
}

__global__ void count_kernel(const int* __restrict__ dst, int* __restrict__ cnt, int nedges) {
    int e = blockIdx.x * 256 + threadIdx.x;
    if (e < nedges) atomicAdd(&cnt[dst[e]], 1);
}

// scan + fused dinv
__global__ void scan_block_kernel(const int* __restrict__ cnt, int* __restrict__ ptr,
                                  int* __restrict__ bsum, float* __restrict__ dinv) {
    __shared__ int s[256];
    int b = blockIdx.x, t = threadIdx.x;
    int i = b * 256 + t;
    int v = (i < NN) ? cnt[i] : 0;
    if (i < NN) dinv[i] = rsqrtf((float)v + 1.0f);  // +1 self-loop
    s[t] = v; __syncthreads();
    for (int off = 1; off < 256; off <<= 1) {
        int x = (t >= off) ? s[t - off] : 0; __syncthreads();
        s[t] += x; __syncthreads();
    }
    if (i < NN) ptr[i] = s[t] - v;
    if (t == 255) bsum[b] = s[255];
}

__global__ void scan_tops_kernel(int* __restrict__ bsum) {
    __shared__ int s[256];
    int t = threadIdx.x;
    int v = (t < NBS) ? bsum[t] : 0;
    s[t] = v; __syncthreads();
    for (int off = 1; off < 256; off <<= 1) {
        int x = (t >= off) ? s[t - off] : 0; __syncthreads();
        s[t] += x; __syncthreads();
    }
    if (t < NBS) bsum[t] = s[t] - v;
}

// scan finalize + seed fill=ptr (csr_fill then uses fill as absolute cursor)
__global__ void scan_add_kernel(int* __restrict__ ptr, int* __restrict__ fill,
                                const int* __restrict__ bsum) {
    int i = blockIdx.x * 256 + threadIdx.x;
    if (i < NN) {
        int p = ptr[i] + bsum[blockIdx.x];
        ptr[i] = p;
        fill[i] = p;
    }
}

__global__ void csr_fill_kernel(const int* __restrict__ src, const int* __restrict__ dst,
                                int* __restrict__ fill, int* __restrict__ csr_src, int nedges) {
    int e = blockIdx.x * 256 + threadIdx.x;
    if (e >= nedges) return;
    int pos = atomicAdd(&fill[dst[e]], 1);
    csr_src[pos] = src[e];
}

// ---------------- register-tiled dense matmul: out = (relu?)(h) @ W [+bias] ----------------
template <int K, int OUT, int WCOLS, bool RELU_IN, bool RELU_OUT, bool BIAS, bool OUT_BF16>
__global__ __launch_bounds__(256) void mm_kernel(
    const float* __restrict__ h, int hstride,
    const float* __restrict__ w, const float* __restrict__ bias,
    float* __restrict__ out, int ostride)
{
    constexpr int KC = 64;
    constexpr int NCH = K / KC;
    constexpr int NCOL = OUT / 4;
    constexpr int NROW = 256 / NCOL;
    constexpr int TM = 64 / NROW;
    __shared__ float sW[KC * OUT];
    __shared__ float sX[64][KC + 4];
    int tid = threadIdx.x;
    int tx = tid % NCOL, ty = tid / NCOL;
    int base = blockIdx.x * 64;
    int r0 = ty * TM;

    float acc[TM][4];
    #pragma unroll
    for (int i = 0; i < TM; ++i) {
        #pragma unroll
        for (int j = 0; j < 4; ++j)
            acc[i][j] = BIAS ? ((tx * 4 + j < WCOLS) ? bias[tx * 4 + j] : 0.0f) : 0.0f;
    }

    for (int ch = 0; ch < NCH; ++ch) {
        int kc = ch * KC;
        if (ch) __syncthreads();
        if constexpr (WCOLS == OUT) {
            for (int i = tid * 4; i < KC * OUT; i += 1024)
                *reinterpret_cast<float4*>(&sW[i]) =
                    *reinterpret_cast<const float4*>(&w[kc * OUT + i]);
        } else {
            for (int i = tid; i < KC * OUT; i += 256) {
                int k = i / OUT, o = i % OUT;
                sW[i] = (o < WCOLS) ? w[(kc + k) * WCOLS + o] : 0.0f;
            }
        }
        for (int i = tid * 4; i < 64 * KC; i += 1024) {
            int r = i / KC, c = i % KC;
            int gn = base + r;
            float4 v = make_float4(0.f, 0.f, 0.f, 0.f);
            if (gn < NN)
                v = *reinterpret_cast<const float4*>(&h[(size_t)gn * hstride + kc + c]);
            if (RELU_IN) {
                v.x = fmaxf(v.x, 0.f); v.y = fmaxf(v.y, 0.f);
                v.z = fmaxf(v.z, 0.f); v.w = fmaxf(v.w, 0.f);
            }
            *reinterpret_cast<float4*>(&sX[r][c]) = v;
        }
        __syncthreads();
        #pragma unroll 2
        for (int kb = 0; kb < KC; kb += 4) {
            float4 wv0 = *reinterpret_cast<const float4*>(&sW[(kb + 0) * OUT + tx * 4]);
            float4 wv1 = *reinterpret_cast<const float4*>(&sW[(kb + 1) * OUT + tx * 4]);
            float4 wv2 = *reinterpret_cast<const float4*>(&sW[(kb + 2) * OUT + tx * 4]);
            float4 wv3 = *reinterpret_cast<const float4*>(&sW[(kb + 3) * OUT + tx * 4]);
            #pragma unroll
            for (int i = 0; i < TM; ++i) {
                float4 xv = *reinterpret_cast<const float4*>(&sX[r0 + i][kb]);
                acc[i][0] = fmaf(xv.x, wv0.x, acc[i][0]);
                acc[i][1] = fmaf(xv.x, wv0.y, acc[i][1]);
                acc[i][2] = fmaf(xv.x, wv0.z, acc[i][2]);
                acc[i][3] = fmaf(xv.x, wv0.w, acc[i][3]);
                acc[i][0] = fmaf(xv.y, wv1.x, acc[i][0]);
                acc[i][1] = fmaf(xv.y, wv1.y, acc[i][1]);
                acc[i][2] = fmaf(xv.y, wv1.z, acc[i][2]);
                acc[i][3] = fmaf(xv.y, wv1.w, acc[i][3]);
                acc[i][0] = fmaf(xv.z, wv2.x, acc[i][0]);
                acc[i][1] = fmaf(xv.z, wv2.y, acc[i][1]);
                acc[i][2] = fmaf(xv.z, wv2.z, acc[i][2]);
                acc[i][3] = fmaf(xv.z, wv2.w, acc[i][3]);
                acc[i][0] = fmaf(xv.w, wv3.x, acc[i][0]);
                acc[i][1] = fmaf(xv.w, wv3.y, acc[i][1]);
                acc[i][2] = fmaf(xv.w, wv3.z, acc[i][2]);
                acc[i][3] = fmaf(xv.w, wv3.w, acc[i][3]);
            }
        }
    }

    #pragma unroll
    for (int i = 0; i < TM; ++i) {
        int gn = base + r0 + i;
        if (gn >= NN) continue;
        float4 v;
        v.x = acc[i][0]; v.y = acc[i][1]; v.z = acc[i][2]; v.w = acc[i][3];
        if (RELU_OUT) {
            v.x = fmaxf(v.x, 0.f); v.y = fmaxf(v.y, 0.f);
            v.z = fmaxf(v.z, 0.f); v.w = fmaxf(v.w, 0.f);
        }
        if constexpr (OUT_BF16) {
            unsigned* orow = reinterpret_cast<unsigned*>(out) + (size_t)gn * (ostride >> 1) + tx * 2;
            uint2 pv;
            pv.x = pack2bf(v.x, v.y);
            pv.y = pack2bf(v.z, v.w);
            *reinterpret_cast<uint2*>(orow) = pv;
        } else {
            *reinterpret_cast<float4*>(&out[(size_t)gn * ostride + tx * 4]) = v;
        }
    }
}

// ---------------- CSR gather, 64 bf16 channels: 32 threads per node ----------------
// hw rows: 32 dwords (64 bf16). No bias (applied downstream in mm1).
__global__ __launch_bounds__(256) void gcn_gather64_bf16_kernel(
    const int* __restrict__ csr_src, const int* __restrict__ ptr, const int* __restrict__ cnt,
    const float* __restrict__ dinv, const unsigned* __restrict__ hw, float* __restrict__ out)
{
    int tid = threadIdx.x;
    int n = blockIdx.x * 8 + (tid >> 5);
    if (n >= NN) return;
    int lane = tid & 31;
    float di = dinv[n];
    unsigned p0 = hw[(size_t)n * 32 + lane];
    float ax = __uint_as_float(p0 << 16) * di * di;
    float ay = __uint_as_float(p0 & 0xffff0000u) * di * di;
    int s0 = ptr[n], c = cnt[n];
    int i = 0;
    for (; i + 3 < c; i += 4) {
        int sa = csr_src[s0 + i + 0];
        int sb = csr_src[s0 + i + 1];
        int sc = csr_src[s0 + i + 2];
        int sd = csr_src[s0 + i + 3];
        float na = dinv[sa] * di, nb = dinv[sb] * di;
        float nc = dinv[sc] * di, nd = dinv[sd] * di;
        unsigned pa = hw[(size_t)sa * 32 + lane];
        unsigned pb = hw[(size_t)sb * 32 + lane];
        unsigned pc = hw[(size_t)sc * 32 + lane];
        unsigned pd = hw[(size_t)sd * 32 + lane];
        ax = fmaf(__uint_as_float(pa << 16), na, ax);
        ay = fmaf(__uint_as_float(pa & 0xffff0000u), na, ay);
        ax = fmaf(__uint_as_float(pb << 16), nb, ax);
        ay = fmaf(__uint_as_float(pb & 0xffff0000u), nb, ay);
        ax = fmaf(__uint_as_float(pc << 16), nc, ax);
        ay = fmaf(__uint_as_float(pc & 0xffff0000u), nc, ay);
        ax = fmaf(__uint_as_float(pd << 16), nd, ax);
        ay = fmaf(__uint_as_float(pd & 0xffff0000u), nd, ay);
    }
    for (; i < c; ++i) {
        int sa = csr_src[s0 + i];
        float na = dinv[sa] * di;
        unsigned pa = hw[(size_t)sa * 32 + lane];
        ax = fmaf(__uint_as_float(pa << 16), na, ax);
        ay = fmaf(__uint_as_float(pa & 0xffff0000u), na, ay);
    }
    float2 r; r.x = ax; r.y = ay;
    *reinterpret_cast<float2*>(out + (size_t)n * 64 + lane * 2) = r;
}

// ---------------- CSR gather, 128 bf16 channels: one wave per node ----------------
__global__ __launch_bounds__(256) void gcn_gather128_bf16_kernel(
    const int* __restrict__ csr_src, const int* __restrict__ ptr, const int* __restrict__ cnt,
    const float* __restrict__ dinv, const unsigned* __restrict__ hw, const float* __restrict__ b,
    float* __restrict__ out)
{
    int tid = threadIdx.x;
    int n = blockIdx.x * 4 + (tid >> 6);
    if (n >= NN) return;
    int lane = tid & 63;
    float di = dinv[n];
    unsigned p0 = hw[(size_t)n * 64 + lane];
    float2 bb = *reinterpret_cast<const float2*>(b + lane * 2);
    float ax = bb.x + __uint_as_float(p0 << 16) * di * di;
    float ay = bb.y + __uint_as_float(p0 & 0xffff0000u) * di * di;
    int s0 = ptr[n], c = cnt[n];
    int i = 0;
    for (; i + 3 < c; i += 4) {
        int sa = csr_src[s0 + i + 0];
        int sb = csr_src[s0 + i + 1];
        int sc = csr_src[s0 + i + 2];
        int sd = csr_src[s0 + i + 3];
        float na = dinv[sa] * di, nb = dinv[sb] * di;
        float nc = dinv[sc] * di, nd = dinv[sd] * di;
        unsigned pa = hw[(size_t)sa * 64 + lane];
        unsigned pb = hw[(size_t)sb * 64 + lane];
        unsigned pc = hw[(size_t)sc * 64 + lane];
        unsigned pd = hw[(size_t)sd * 64 + lane];
        ax = fmaf(__uint_as_float(pa << 16), na, ax);
        ay = fmaf(__uint_as_float(pa & 0xffff0000u), na, ay);
        ax = fmaf(__uint_as_float(pb << 16), nb, ax);
        ay = fmaf(__uint_as_float(pb & 0xffff0000u), nb, ay);
        ax = fmaf(__uint_as_float(pc << 16), nc, ax);
        ay = fmaf(__uint_as_float(pc & 0xffff0000u), nc, ay);
        ax = fmaf(__uint_as_float(pd << 16), nd, ax);
        ay = fmaf(__uint_as_float(pd & 0xffff0000u), nd, ay);
    }
    for (; i < c; ++i) {
        int sa = csr_src[s0 + i];
        float na = dinv[sa] * di;
        unsigned pa = hw[(size_t)sa * 64 + lane];
        ax = fmaf(__uint_as_float(pa << 16), na, ax);
        ay = fmaf(__uint_as_float(pa & 0xffff0000u), na, ay);
    }
    float2 r; r.x = ax; r.y = ay;
    *reinterpret_cast<float2*>(out + (size_t)n * 128 + lane * 2) = r;
}

// ---------------- CSR gather, 10 channels (stride 16): 16 threads per node ----------------
__global__ void gcn_gather10_kernel(
    const int* __restrict__ csr_src, const int* __restrict__ ptr, const int* __restrict__ cnt,
    const float* __restrict__ dinv, const float* __restrict__ hw, const float* __restrict__ b,
    float* __restrict__ out)
{
    int idx = blockIdx.x * 256 + threadIdx.x;
    int n = idx >> 4;
    int ch = idx & 15;
    if (n >= NN || ch >= 10) return;
    float di = dinv[n];
    float acc = b[ch] + hw[n * 16 + ch] * di * di;
    int s0 = ptr[n], c = cnt[n];
    for (int i = 0; i < c; ++i) {
        int s = csr_src[s0 + i];
        acc += hw[s * 16 + ch] * (dinv[s] * di);
    }
    out[n * 16 + ch] = acc;
}

// ---------------- fused segmented pool + log_softmax (batch is sorted) ----------------
__global__ __launch_bounds__(256) void pool_ls_kernel(
    const float* __restrict__ h3, const int* __restrict__ batch, float* __restrict__ out)
{
    __shared__ int seg[2];
    __shared__ float red[16][17];
    int g = blockIdx.x;
    int t = threadIdx.x;
    if (t < 2) {
        int target = g + t;
        int lo = 0, hi = NN;
        while (lo < hi) {
            int mid = (lo + hi) >> 1;
            if (batch[mid] < target) lo = mid + 1; else hi = mid;
        }
        seg[t] = lo;
    }
    __syncthreads();
    int s = seg[0], e = seg[1];
    int ch = t & 15, nl = t >> 4;
    float acc = 0.0f;
    for (int n = s + nl; n < e; n += 16)
        if (ch < 10) acc += h3[(size_t)n * 16 + ch];
    red[nl][ch] = acc;
    __syncthreads();
    if (t < 16) {
        float ssum = 0.0f;
        #pragma unroll
        for (int i = 0; i < 16; ++i) ssum += red[i][t];
        red[0][t] = ssum;
    }
    __syncthreads();
    if (t == 0) {
        float c = fmaxf((float)(e - s), 1.0f);
        float v[10], m = -1e30f;
        #pragma unroll
        for (int i = 0; i < 10; ++i) { v[i] = red[0][i] / c; m = fmaxf(m, v[i]); }
        float ssum = 0.0f;
        #pragma unroll
        for (int i = 0; i < 10; ++i) ssum += expf(v[i] - m);
        float lse = m + logf(ssum);
        #pragma unroll
        for (int i = 0; i < 10; ++i) out[g * 10 + i] = v[i] - lse;
    }
}

extern "C" void kernel_launch(void* const* d_in, const int* in_sizes, int n_in,
                              void* d_out, int out_size, void* d_ws, size_t ws_size,
                              hipStream_t stream)
{
    const float* x      = (const float*)d_in[0];
    const int*   ei     = (const int*)d_in[1];
    const int*   batch  = (const int*)d_in[2];
    const float* emb_w1 = (const float*)d_in[3];
    const float* emb_b1 = (const float*)d_in[4];
    const float* emb_w2 = (const float*)d_in[5];
    const float* emb_b2 = (const float*)d_in[6];
    const float* w1     = (const float*)d_in[7];
    const float* b1     = (const float*)d_in[8];
    const float* w2     = (const float*)d_in[9];
    const float* b2     = (const float*)d_in[10];
    const float* w3     = (const float*)d_in[11];
    const float* b3     = (const float*)d_in[12];

    int E = in_sizes[1] / 2;
    const int* src = ei;
    const int* dst = ei + E;

    // workspace layout (~55.3 MB total)
    char* ws = (char*)d_ws;
    size_t off = 0;
    float*    H1   = (float*)(ws + off);    off += (size_t)NN * 128 * 4;  // fp32 [NN,128]
    unsigned* HWB  = (unsigned*)(ws + off); off += (size_t)NN * 64 * 4;   // bf16 [NN,128] / bf16 [NN,64] / f32 [NN,16]
    float*    A64  = (float*)(ws + off);    off += (size_t)NN * 64 * 4;   // fp32 [NN,64] / f32 [NN,16]
    float*    dinv = (float*)(ws + off);    off += (size_t)NN * 4;
    int*      cnt  = (int*)(ws + off);      off += (size_t)NN * 4;
    int*      ptr  = (int*)(ws + off);      off += (size_t)NN * 4;
    int*      fill = (int*)(ws + off);      off += (size_t)NN * 4;
    int*      bsum = (int*)(ws + off);      off += 256 * 4;
    int*      csrs = (int*)(ws + off);      off += (size_t)E * 4;

    int mmgrid = cdiv(NN, 64);

    // ---- CSR build ----
    zero_int_kernel<<<cdiv(NN, 256), 256, 0, stream>>>(cnt);
    count_kernel<<<cdiv(E, 256), 256, 0, stream>>>(dst, cnt, E);
    scan_block_kernel<<<NBS, 256, 0, stream>>>(cnt, ptr, bsum, dinv);
    scan_tops_kernel<<<1, 256, 0, stream>>>(bsum);
    scan_add_kernel<<<NBS, 256, 0, stream>>>(ptr, fill, bsum);
    csr_fill_kernel<<<cdiv(E, 256), 256, 0, stream>>>(src, dst, fill, csrs, E);

    // ---- embedder: x -> A64 (f32) -> HWB (bf16 [NN,64]) ----
    mm_kernel<64, 64, 64, false, true, true, false><<<mmgrid, 256, 0, stream>>>(x, 64, emb_w1, emb_b1, A64, 64);
    mm_kernel<64, 64, 64, false, true, true, true><<<mmgrid, 256, 0, stream>>>(A64, 64, emb_w2, emb_b2, (float*)HWB, 64);

    // ---- layer 1 reordered: aggregate 64-dim, then matmul (+b1, relu) ----
    gcn_gather64_bf16_kernel<<<cdiv(NN, 8), 256, 0, stream>>>(csrs, ptr, cnt, dinv, HWB, A64);
    mm_kernel<64, 128, 128, false, true, true, false><<<mmgrid, 256, 0, stream>>>(A64, 64, w1, b1, H1, 128);

    // ---- layer 2: matmul (h1 already relu'd) -> bf16, aggregate 128-dim (+b2) ----
    mm_kernel<128, 128, 128, false, false, false, true><<<mmgrid, 256, 0, stream>>>(H1, 128, w2, nullptr, (float*)HWB, 128);
    gcn_gather128_bf16_kernel<<<cdiv(NN, 4), 256, 0, stream>>>(csrs, ptr, cnt, dinv, HWB, b2, H1);

    // ---- layer 3: 128 -> 10 (relu_in), aggregate 10-dim (+b3) ----
    mm_kernel<128, 16, 10, true, false, false, false><<<mmgrid, 256, 0, stream>>>(H1, 128, w3, nullptr, A64, 16);
    gcn_gather10_kernel<<<cdiv(NN * 16, 256), 256, 0, stream>>>(csrs, ptr, cnt, dinv, A64, b3, (float*)HWB);

    // ---- fused pooling + log_softmax (one block per graph) ----
    pool_ls_kernel<<<NG, 256, 0, stream>>>((float*)HWB, batch, (float*)d_out);
}

// Round 8
// 275.870 us; speedup vs baseline: 1.0849x; 1.0470x over previous
//
#include <hip/hip_runtime.h>
#include <math.h>

#define NN 50000      // nodes
#define NG 500        // graphs
#define CC 10
#define NBS 196       // cdiv(NN,256) scan blocks
#define NRANGE 8      // dst-range partitions (~XCD count)
#define RSIZE 6250    // NN / NRANGE

static inline int cdiv(int a, int b) { return (a + b - 1) / b; }

__device__ inline unsigned bf16rne(float f) {
    unsigned u = __float_as_uint(f);
    return (u + 0x7fffu + ((u >> 16) & 1u)) >> 16;
}
__device__ inline unsigned pack2bf(float a, float b) {
    return bf16rne(a) | (bf16rne(b) << 16);
}

// ---------------- CSR build ----------------
__global__ void zero_int_kernel(int* __restrict__ a) {
    int i = blockIdx.x * 256 + threadIdx.x;
    if (i < NN) a[i] = 0;
}

// dst-range partitioned count: blocks with blockIdx%8==r handle dst in [r*RSIZE,(r+1)*RSIZE)
// -> all writers of a cnt cache line live on one XCD (heuristic), killing cross-XCD
//    partial-line writebacks.
__global__ void count_part_kernel(const int* __restrict__ dst, int* __restrict__ cnt, int nedges) {
    int r = blockIdx.x & (NRANGE - 1);
    int e = (blockIdx.x >> 3) * 256 + threadIdx.x;
    if (e >= nedges) return;
    int d = dst[e];
    if (d / RSIZE != r) return;
    atomicAdd(&cnt[d], 1);
}

// scan + fused dinv
__global__ void scan_block_kernel(const int* __restrict__ cnt, int* __restrict__ ptr,
                                  int* __restrict__ bsum, float* __restrict__ dinv) {
    __shared__ int s[256];
    int b = blockIdx.x, t = threadIdx.x;
    int i = b * 256 + t;
    int v = (i < NN) ? cnt[i] : 0;
    if (i < NN) dinv[i] = rsqrtf((float)v + 1.0f);  // +1 self-loop
    s[t] = v; __syncthreads();
    for (int off = 1; off < 256; off <<= 1) {
        int x = (t >= off) ? s[t - off] : 0; __syncthreads();
        s[t] += x; __syncthreads();
    }
    if (i < NN) ptr[i] = s[t] - v;
    if (t == 255) bsum[b] = s[255];
}

__global__ void scan_tops_kernel(int* __restrict__ bsum) {
    __shared__ int s[256];
    int t = threadIdx.x;
    int v = (t < NBS) ? bsum[t] : 0;
    s[t] = v; __syncthreads();
    for (int off = 1; off < 256; off <<= 1) {
        int x = (t >= off) ? s[t - off] : 0; __syncthreads();
        s[t] += x; __syncthreads();
    }
    if (t < NBS) bsum[t] = s[t] - v;
}

// scan finalize + seed fill=ptr
__global__ void scan_add_kernel(int* __restrict__ ptr, int* __restrict__ fill,
                                const int* __restrict__ bsum) {
    int i = blockIdx.x * 256 + threadIdx.x;
    if (i < NN) {
        int p = ptr[i] + bsum[blockIdx.x];
        ptr[i] = p;
        fill[i] = p;
    }
}

// dst-range partitioned fill: csr_src lines for range r written only by range-r blocks
__global__ void csr_fill_part_kernel(const int* __restrict__ src, const int* __restrict__ dst,
                                     int* __restrict__ fill, int* __restrict__ csr_src, int nedges) {
    int r = blockIdx.x & (NRANGE - 1);
    int e = (blockIdx.x >> 3) * 256 + threadIdx.x;
    if (e >= nedges) return;
    int d = dst[e];
    if (d / RSIZE != r) return;
    int pos = atomicAdd(&fill[d], 1);
    csr_src[pos] = src[e];
}

// ---------------- register-tiled dense matmul: out = (relu?)(h) @ W [+bias] ----------------
template <int K, int OUT, int WCOLS, bool RELU_IN, bool RELU_OUT, bool BIAS, bool OUT_BF16>
__global__ __launch_bounds__(256) void mm_kernel(
    const float* __restrict__ h, int hstride,
    const float* __restrict__ w, const float* __restrict__ bias,
    float* __restrict__ out, int ostride)
{
    constexpr int KC = 64;
    constexpr int NCH = K / KC;
    constexpr int NCOL = OUT / 4;
    constexpr int NROW = 256 / NCOL;
    constexpr int TM = 64 / NROW;
    __shared__ float sW[KC * OUT];
    __shared__ float sX[64][KC + 4];
    int tid = threadIdx.x;
    int tx = tid % NCOL, ty = tid / NCOL;
    int base = blockIdx.x * 64;
    int r0 = ty * TM;

    float acc[TM][4];
    #pragma unroll
    for (int i = 0; i < TM; ++i) {
        #pragma unroll
        for (int j = 0; j < 4; ++j)
            acc[i][j] = BIAS ? ((tx * 4 + j < WCOLS) ? bias[tx * 4 + j] : 0.0f) : 0.0f;
    }

    for (int ch = 0; ch < NCH; ++ch) {
        int kc = ch * KC;
        if (ch) __syncthreads();
        if constexpr (WCOLS == OUT) {
            for (int i = tid * 4; i < KC * OUT; i += 1024)
                *reinterpret_cast<float4*>(&sW[i]) =
                    *reinterpret_cast<const float4*>(&w[kc * OUT + i]);
        } else {
            for (int i = tid; i < KC * OUT; i += 256) {
                int k = i / OUT, o = i % OUT;
                sW[i] = (o < WCOLS) ? w[(kc + k) * WCOLS + o] : 0.0f;
            }
        }
        for (int i = tid * 4; i < 64 * KC; i += 1024) {
            int r = i / KC, c = i % KC;
            int gn = base + r;
            float4 v = make_float4(0.f, 0.f, 0.f, 0.f);
            if (gn < NN)
                v = *reinterpret_cast<const float4*>(&h[(size_t)gn * hstride + kc + c]);
            if (RELU_IN) {
                v.x = fmaxf(v.x, 0.f); v.y = fmaxf(v.y, 0.f);
                v.z = fmaxf(v.z, 0.f); v.w = fmaxf(v.w, 0.f);
            }
            *reinterpret_cast<float4*>(&sX[r][c]) = v;
        }
        __syncthreads();
        #pragma unroll 2
        for (int kb = 0; kb < KC; kb += 4) {
            float4 wv0 = *reinterpret_cast<const float4*>(&sW[(kb + 0) * OUT + tx * 4]);
            float4 wv1 = *reinterpret_cast<const float4*>(&sW[(kb + 1) * OUT + tx * 4]);
            float4 wv2 = *reinterpret_cast<const float4*>(&sW[(kb + 2) * OUT + tx * 4]);
            float4 wv3 = *reinterpret_cast<const float4*>(&sW[(kb + 3) * OUT + tx * 4]);
            #pragma unroll
            for (int i = 0; i < TM; ++i) {
                float4 xv = *reinterpret_cast<const float4*>(&sX[r0 + i][kb]);
                acc[i][0] = fmaf(xv.x, wv0.x, acc[i][0]);
                acc[i][1] = fmaf(xv.x, wv0.y, acc[i][1]);
                acc[i][2] = fmaf(xv.x, wv0.z, acc[i][2]);
                acc[i][3] = fmaf(xv.x, wv0.w, acc[i][3]);
                acc[i][0] = fmaf(xv.y, wv1.x, acc[i][0]);
                acc[i][1] = fmaf(xv.y, wv1.y, acc[i][1]);
                acc[i][2] = fmaf(xv.y, wv1.z, acc[i][2]);
                acc[i][3] = fmaf(xv.y, wv1.w, acc[i][3]);
                acc[i][0] = fmaf(xv.z, wv2.x, acc[i][0]);
                acc[i][1] = fmaf(xv.z, wv2.y, acc[i][1]);
                acc[i][2] = fmaf(xv.z, wv2.z, acc[i][2]);
                acc[i][3] = fmaf(xv.z, wv2.w, acc[i][3]);
                acc[i][0] = fmaf(xv.w, wv3.x, acc[i][0]);
                acc[i][1] = fmaf(xv.w, wv3.y, acc[i][1]);
                acc[i][2] = fmaf(xv.w, wv3.z, acc[i][2]);
                acc[i][3] = fmaf(xv.w, wv3.w, acc[i][3]);
            }
        }
    }

    #pragma unroll
    for (int i = 0; i < TM; ++i) {
        int gn = base + r0 + i;
        if (gn >= NN) continue;
        float4 v;
        v.x = acc[i][0]; v.y = acc[i][1]; v.z = acc[i][2]; v.w = acc[i][3];
        if (RELU_OUT) {
            v.x = fmaxf(v.x, 0.f); v.y = fmaxf(v.y, 0.f);
            v.z = fmaxf(v.z, 0.f); v.w = fmaxf(v.w, 0.f);
        }
        if constexpr (OUT_BF16) {
            unsigned* orow = reinterpret_cast<unsigned*>(out) + (size_t)gn * (ostride >> 1) + tx * 2;
            uint2 pv;
            pv.x = pack2bf(v.x, v.y);
            pv.y = pack2bf(v.z, v.w);
            *reinterpret_cast<uint2*>(orow) = pv;
        } else {
            *reinterpret_cast<float4*>(&out[(size_t)gn * ostride + tx * 4]) = v;
        }
    }
}

// ---------------- CSR gather, 64 bf16 channels: 32 threads per node ----------------
__global__ __launch_bounds__(256) void gcn_gather64_bf16_kernel(
    const int* __restrict__ csr_src, const int* __restrict__ ptr, const int* __restrict__ cnt,
    const float* __restrict__ dinv, const unsigned* __restrict__ hw, float* __restrict__ out)
{
    int tid = threadIdx.x;
    int n = blockIdx.x * 8 + (tid >> 5);
    if (n >= NN) return;
    int lane = tid & 31;
    float di = dinv[n];
    unsigned p0 = hw[(size_t)n * 32 + lane];
    float ax = __uint_as_float(p0 << 16) * di * di;
    float ay = __uint_as_float(p0 & 0xffff0000u) * di * di;
    int s0 = ptr[n], c = cnt[n];
    int i = 0;
    for (; i + 3 < c; i += 4) {
        int sa = csr_src[s0 + i + 0];
        int sb = csr_src[s0 + i + 1];
        int sc = csr_src[s0 + i + 2];
        int sd = csr_src[s0 + i + 3];
        float na = dinv[sa] * di, nb = dinv[sb] * di;
        float nc = dinv[sc] * di, nd = dinv[sd] * di;
        unsigned pa = hw[(size_t)sa * 32 + lane];
        unsigned pb = hw[(size_t)sb * 32 + lane];
        unsigned pc = hw[(size_t)sc * 32 + lane];
        unsigned pd = hw[(size_t)sd * 32 + lane];
        ax = fmaf(__uint_as_float(pa << 16), na, ax);
        ay = fmaf(__uint_as_float(pa & 0xffff0000u), na, ay);
        ax = fmaf(__uint_as_float(pb << 16), nb, ax);
        ay = fmaf(__uint_as_float(pb & 0xffff0000u), nb, ay);
        ax = fmaf(__uint_as_float(pc << 16), nc, ax);
        ay = fmaf(__uint_as_float(pc & 0xffff0000u), nc, ay);
        ax = fmaf(__uint_as_float(pd << 16), nd, ax);
        ay = fmaf(__uint_as_float(pd & 0xffff0000u), nd, ay);
    }
    for (; i < c; ++i) {
        int sa = csr_src[s0 + i];
        float na = dinv[sa] * di;
        unsigned pa = hw[(size_t)sa * 32 + lane];
        ax = fmaf(__uint_as_float(pa << 16), na, ax);
        ay = fmaf(__uint_as_float(pa & 0xffff0000u), na, ay);
    }
    float2 r; r.x = ax; r.y = ay;
    *reinterpret_cast<float2*>(out + (size_t)n * 64 + lane * 2) = r;
}

// ---------------- CSR gather, 128 bf16 channels: one wave per node ----------------
__global__ __launch_bounds__(256) void gcn_gather128_bf16_kernel(
    const int* __restrict__ csr_src, const int* __restrict__ ptr, const int* __restrict__ cnt,
    const float* __restrict__ dinv, const unsigned* __restrict__ hw, const float* __restrict__ b,
    float* __restrict__ out)
{
    int tid = threadIdx.x;
    int n = blockIdx.x * 4 + (tid >> 6);
    if (n >= NN) return;
    int lane = tid & 63;
    float di = dinv[n];
    unsigned p0 = hw[(size_t)n * 64 + lane];
    float2 bb = *reinterpret_cast<const float2*>(b + lane * 2);
    float ax = bb.x + __uint_as_float(p0 << 16) * di * di;
    float ay = bb.y + __uint_as_float(p0 & 0xffff0000u) * di * di;
    int s0 = ptr[n], c = cnt[n];
    int i = 0;
    for (; i + 3 < c; i += 4) {
        int sa = csr_src[s0 + i + 0];
        int sb = csr_src[s0 + i + 1];
        int sc = csr_src[s0 + i + 2];
        int sd = csr_src[s0 + i + 3];
        float na = dinv[sa] * di, nb = dinv[sb] * di;
        float nc = dinv[sc] * di, nd = dinv[sd] * di;
        unsigned pa = hw[(size_t)sa * 64 + lane];
        unsigned pb = hw[(size_t)sb * 64 + lane];
        unsigned pc = hw[(size_t)sc * 64 + lane];
        unsigned pd = hw[(size_t)sd * 64 + lane];
        ax = fmaf(__uint_as_float(pa << 16), na, ax);
        ay = fmaf(__uint_as_float(pa & 0xffff0000u), na, ay);
        ax = fmaf(__uint_as_float(pb << 16), nb, ax);
        ay = fmaf(__uint_as_float(pb & 0xffff0000u), nb, ay);
        ax = fmaf(__uint_as_float(pc << 16), nc, ax);
        ay = fmaf(__uint_as_float(pc & 0xffff0000u), nc, ay);
        ax = fmaf(__uint_as_float(pd << 16), nd, ax);
        ay = fmaf(__uint_as_float(pd & 0xffff0000u), nd, ay);
    }
    for (; i < c; ++i) {
        int sa = csr_src[s0 + i];
        float na = dinv[sa] * di;
        unsigned pa = hw[(size_t)sa * 64 + lane];
        ax = fmaf(__uint_as_float(pa << 16), na, ax);
        ay = fmaf(__uint_as_float(pa & 0xffff0000u), na, ay);
    }
    float2 r; r.x = ax; r.y = ay;
    *reinterpret_cast<float2*>(out + (size_t)n * 128 + lane * 2) = r;
}

// ---------------- CSR gather, 10 channels (stride 16): 16 threads per node ----------------
__global__ void gcn_gather10_kernel(
    const int* __restrict__ csr_src, const int* __restrict__ ptr, const int* __restrict__ cnt,
    const float* __restrict__ dinv, const float* __restrict__ hw, const float* __restrict__ b,
    float* __restrict__ out)
{
    int idx = blockIdx.x * 256 + threadIdx.x;
    int n = idx >> 4;
    int ch = idx & 15;
    if (n >= NN || ch >= 10) return;
    float di = dinv[n];
    float acc = b[ch] + hw[n * 16 + ch] * di * di;
    int s0 = ptr[n], c = cnt[n];
    for (int i = 0; i < c; ++i) {
        int s = csr_src[s0 + i];
        acc += hw[s * 16 + ch] * (dinv[s] * di);
    }
    out[n * 16 + ch] = acc;
}

// ---------------- fused segmented pool + log_softmax (batch is sorted) ----------------
__global__ __launch_bounds__(256) void pool_ls_kernel(
    const float* __restrict__ h3, const int* __restrict__ batch, float* __restrict__ out)
{
    __shared__ int seg[2];
    __shared__ float red[16][17];
    int g = blockIdx.x;
    int t = threadIdx.x;
    if (t < 2) {
        int target = g + t;
        int lo = 0, hi = NN;
        while (lo < hi) {
            int mid = (lo + hi) >> 1;
            if (batch[mid] < target) lo = mid + 1; else hi = mid;
        }
        seg[t] = lo;
    }
    __syncthreads();
    int s = seg[0], e = seg[1];
    int ch = t & 15, nl = t >> 4;
    float acc = 0.0f;
    for (int n = s + nl; n < e; n += 16)
        if (ch < 10) acc += h3[(size_t)n * 16 + ch];
    red[nl][ch] = acc;
    __syncthreads();
    if (t < 16) {
        float ssum = 0.0f;
        #pragma unroll
        for (int i = 0; i < 16; ++i) ssum += red[i][t];
        red[0][t] = ssum;
    }
    __syncthreads();
    if (t == 0) {
        float c = fmaxf((float)(e - s), 1.0f);
        float v[10], m = -1e30f;
        #pragma unroll
        for (int i = 0; i < 10; ++i) { v[i] = red[0][i] / c; m = fmaxf(m, v[i]); }
        float ssum = 0.0f;
        #pragma unroll
        for (int i = 0; i < 10; ++i) ssum += expf(v[i] - m);
        float lse = m + logf(ssum);
        #pragma unroll
        for (int i = 0; i < 10; ++i) out[g * 10 + i] = v[i] - lse;
    }
}

extern "C" void kernel_launch(void* const* d_in, const int* in_sizes, int n_in,
                              void* d_out, int out_size, void* d_ws, size_t ws_size,
                              hipStream_t stream)
{
    const float* x      = (const float*)d_in[0];
    const int*   ei     = (const int*)d_in[1];
    const int*   batch  = (const int*)d_in[2];
    const float* emb_w1 = (const float*)d_in[3];
    const float* emb_b1 = (const float*)d_in[4];
    const float* emb_w2 = (const float*)d_in[5];
    const float* emb_b2 = (const float*)d_in[6];
    const float* w1     = (const float*)d_in[7];
    const float* b1     = (const float*)d_in[8];
    const float* w2     = (const float*)d_in[9];
    const float* b2     = (const float*)d_in[10];
    const float* w3     = (const float*)d_in[11];
    const float* b3     = (const float*)d_in[12];

    int E = in_sizes[1] / 2;
    const int* src = ei;
    const int* dst = ei + E;

    // workspace layout (~55.3 MB total)
    char* ws = (char*)d_ws;
    size_t off = 0;
    float*    H1   = (float*)(ws + off);    off += (size_t)NN * 128 * 4;  // fp32 [NN,128]
    unsigned* HWB  = (unsigned*)(ws + off); off += (size_t)NN * 64 * 4;   // bf16 [NN,128] / bf16 [NN,64] / f32 [NN,16]
    float*    A64  = (float*)(ws + off);    off += (size_t)NN * 64 * 4;   // fp32 [NN,64] / f32 [NN,16]
    float*    dinv = (float*)(ws + off);    off += (size_t)NN * 4;
    int*      cnt  = (int*)(ws + off);      off += (size_t)NN * 4;
    int*      ptr  = (int*)(ws + off);      off += (size_t)NN * 4;
    int*      fill = (int*)(ws + off);      off += (size_t)NN * 4;
    int*      bsum = (int*)(ws + off);      off += 256 * 4;
    int*      csrs = (int*)(ws + off);      off += (size_t)E * 4;

    int mmgrid = cdiv(NN, 64);
    int egrid_part = cdiv(E, 256) * NRANGE;

    // ---- CSR build (dst-range × XCD partitioned atomics/stores) ----
    zero_int_kernel<<<cdiv(NN, 256), 256, 0, stream>>>(cnt);
    count_part_kernel<<<egrid_part, 256, 0, stream>>>(dst, cnt, E);
    scan_block_kernel<<<NBS, 256, 0, stream>>>(cnt, ptr, bsum, dinv);
    scan_tops_kernel<<<1, 256, 0, stream>>>(bsum);
    scan_add_kernel<<<NBS, 256, 0, stream>>>(ptr, fill, bsum);
    csr_fill_part_kernel<<<egrid_part, 256, 0, stream>>>(src, dst, fill, csrs, E);

    // ---- embedder: x -> A64 (f32) -> HWB (bf16 [NN,64]) ----
    mm_kernel<64, 64, 64, false, true, true, false><<<mmgrid, 256, 0, stream>>>(x, 64, emb_w1, emb_b1, A64, 64);
    mm_kernel<64, 64, 64, false, true, true, true><<<mmgrid, 256, 0, stream>>>(A64, 64, emb_w2, emb_b2, (float*)HWB, 64);

    // ---- layer 1 reordered: aggregate 64-dim, then matmul (+b1, relu) ----
    gcn_gather64_bf16_kernel<<<cdiv(NN, 8), 256, 0, stream>>>(csrs, ptr, cnt, dinv, HWB, A64);
    mm_kernel<64, 128, 128, false, true, true, false><<<mmgrid, 256, 0, stream>>>(A64, 64, w1, b1, H1, 128);

    // ---- layer 2: matmul -> bf16, aggregate 128-dim (+b2) ----
    mm_kernel<128, 128, 128, false, false, false, true><<<mmgrid, 256, 0, stream>>>(H1, 128, w2, nullptr, (float*)HWB, 128);
    gcn_gather128_bf16_kernel<<<cdiv(NN, 4), 256, 0, stream>>>(csrs, ptr, cnt, dinv, HWB, b2, H1);

    // ---- layer 3: 128 -> 10 (relu_in), aggregate 10-dim (+b3) ----
    mm_kernel<128, 16, 10, true, false, false, false><<<mmgrid, 256, 0, stream>>>(H1, 128, w3, nullptr, A64, 16);
    gcn_gather10_kernel<<<cdiv(NN * 16, 256), 256, 0, stream>>>(csrs, ptr, cnt, dinv, A64, b3, (float*)HWB);

    // ---- fused pooling + log_softmax (one block per graph) ----
    pool_ls_kernel<<<NG, 256, 0, stream>>>((float*)HWB, batch, (float*)d_out);
}

// Round 9
// 269.226 us; speedup vs baseline: 1.1117x; 1.0247x over previous
//
#include <hip/hip_runtime.h>
#include <math.h>

#define NN 50000      // nodes
#define NG 500        // graphs
#define CC 10
#define NBS 196       // cdiv(NN,256) scan blocks
#define NRANGE 8      // dst-range partitions (~XCD count)
#define RSIZE 6250    // NN / NRANGE

static inline int cdiv(int a, int b) { return (a + b - 1) / b; }

__device__ inline unsigned bf16rne(float f) {
    unsigned u = __float_as_uint(f);
    return (u + 0x7fffu + ((u >> 16) & 1u)) >> 16;
}
__device__ inline unsigned pack2bf(float a, float b) {
    return bf16rne(a) | (bf16rne(b) << 16);
}

// ---------------- CSR build ----------------
__global__ void zero_int_kernel(int* __restrict__ a) {
    int i = blockIdx.x * 256 + threadIdx.x;
    if (i < NN) a[i] = 0;
}

__global__ void count_part_kernel(const int* __restrict__ dst, int* __restrict__ cnt, int nedges) {
    int r = blockIdx.x & (NRANGE - 1);
    int e = (blockIdx.x >> 3) * 256 + threadIdx.x;
    if (e >= nedges) return;
    int d = dst[e];
    if (d / RSIZE != r) return;
    atomicAdd(&cnt[d], 1);
}

// scan + fused dinv
__global__ void scan_block_kernel(const int* __restrict__ cnt, int* __restrict__ ptr,
                                  int* __restrict__ bsum, float* __restrict__ dinv) {
    __shared__ int s[256];
    int b = blockIdx.x, t = threadIdx.x;
    int i = b * 256 + t;
    int v = (i < NN) ? cnt[i] : 0;
    if (i < NN) dinv[i] = rsqrtf((float)v + 1.0f);  // +1 self-loop
    s[t] = v; __syncthreads();
    for (int off = 1; off < 256; off <<= 1) {
        int x = (t >= off) ? s[t - off] : 0; __syncthreads();
        s[t] += x; __syncthreads();
    }
    if (i < NN) ptr[i] = s[t] - v;
    if (t == 255) bsum[b] = s[255];
}

__global__ void scan_tops_kernel(int* __restrict__ bsum) {
    __shared__ int s[256];
    int t = threadIdx.x;
    int v = (t < NBS) ? bsum[t] : 0;
    s[t] = v; __syncthreads();
    for (int off = 1; off < 256; off <<= 1) {
        int x = (t >= off) ? s[t - off] : 0; __syncthreads();
        s[t] += x; __syncthreads();
    }
    if (t < NBS) bsum[t] = s[t] - v;
}

__global__ void scan_add_kernel(int* __restrict__ ptr, int* __restrict__ fill,
                                const int* __restrict__ bsum) {
    int i = blockIdx.x * 256 + threadIdx.x;
    if (i < NN) {
        int p = ptr[i] + bsum[blockIdx.x];
        ptr[i] = p;
        fill[i] = p;
    }
}

__global__ void csr_fill_part_kernel(const int* __restrict__ src, const int* __restrict__ dst,
                                     int* __restrict__ fill, int* __restrict__ csr_src, int nedges) {
    int r = blockIdx.x & (NRANGE - 1);
    int e = (blockIdx.x >> 3) * 256 + threadIdx.x;
    if (e >= nedges) return;
    int d = dst[e];
    if (d / RSIZE != r) return;
    int pos = atomicAdd(&fill[d], 1);
    csr_src[pos] = src[e];
}

// ---------------- fused MLP embedder: x -> relu(xW1+b1) -> relu(.W2+b2)*dinv -> bf16 ----------------
__global__ __launch_bounds__(256) void emb_fused_kernel(
    const float* __restrict__ x,
    const float* __restrict__ w1, const float* __restrict__ b1,
    const float* __restrict__ w2, const float* __restrict__ b2,
    const float* __restrict__ dinv, unsigned* __restrict__ out /* bf16 [NN,64] */)
{
    __shared__ float sW1[64 * 64];
    __shared__ float sW2[64 * 64];
    __shared__ float sB[128];
    __shared__ float sX[64][68];
    __shared__ float sH[64][68];
    int tid = threadIdx.x;
    int base = blockIdx.x * 64;
    for (int i = tid * 4; i < 64 * 64; i += 1024) {
        *reinterpret_cast<float4*>(&sW1[i]) = *reinterpret_cast<const float4*>(&w1[i]);
        *reinterpret_cast<float4*>(&sW2[i]) = *reinterpret_cast<const float4*>(&w2[i]);
    }
    if (tid < 64) sB[tid] = b1[tid];
    else if (tid < 128) sB[tid] = b2[tid - 64];
    for (int i = tid * 4; i < 64 * 64; i += 1024) {
        int r = i >> 6, c = i & 63;
        int gn = base + r;
        float4 v = make_float4(0.f, 0.f, 0.f, 0.f);
        if (gn < NN) v = *reinterpret_cast<const float4*>(&x[(size_t)gn * 64 + c]);
        *reinterpret_cast<float4*>(&sX[r][c]) = v;
    }
    __syncthreads();
    int tx = tid & 15, ty = tid >> 4;
    int r0 = ty * 4;
    // stage 1: h1 = relu(X @ W1 + b1) -> sH
    {
        float acc[4][4];
        #pragma unroll
        for (int i = 0; i < 4; ++i)
            #pragma unroll
            for (int j = 0; j < 4; ++j) acc[i][j] = sB[tx * 4 + j];
        #pragma unroll 2
        for (int kb = 0; kb < 64; kb += 4) {
            float4 wv0 = *reinterpret_cast<const float4*>(&sW1[(kb + 0) * 64 + tx * 4]);
            float4 wv1 = *reinterpret_cast<const float4*>(&sW1[(kb + 1) * 64 + tx * 4]);
            float4 wv2 = *reinterpret_cast<const float4*>(&sW1[(kb + 2) * 64 + tx * 4]);
            float4 wv3 = *reinterpret_cast<const float4*>(&sW1[(kb + 3) * 64 + tx * 4]);
            #pragma unroll
            for (int i = 0; i < 4; ++i) {
                float4 xv = *reinterpret_cast<const float4*>(&sX[r0 + i][kb]);
                acc[i][0] = fmaf(xv.x, wv0.x, acc[i][0]); acc[i][1] = fmaf(xv.x, wv0.y, acc[i][1]);
                acc[i][2] = fmaf(xv.x, wv0.z, acc[i][2]); acc[i][3] = fmaf(xv.x, wv0.w, acc[i][3]);
                acc[i][0] = fmaf(xv.y, wv1.x, acc[i][0]); acc[i][1] = fmaf(xv.y, wv1.y, acc[i][1]);
                acc[i][2] = fmaf(xv.y, wv1.z, acc[i][2]); acc[i][3] = fmaf(xv.y, wv1.w, acc[i][3]);
                acc[i][0] = fmaf(xv.z, wv2.x, acc[i][0]); acc[i][1] = fmaf(xv.z, wv2.y, acc[i][1]);
                acc[i][2] = fmaf(xv.z, wv2.z, acc[i][2]); acc[i][3] = fmaf(xv.z, wv2.w, acc[i][3]);
                acc[i][0] = fmaf(xv.w, wv3.x, acc[i][0]); acc[i][1] = fmaf(xv.w, wv3.y, acc[i][1]);
                acc[i][2] = fmaf(xv.w, wv3.z, acc[i][2]); acc[i][3] = fmaf(xv.w, wv3.w, acc[i][3]);
            }
        }
        __syncthreads();  // sX readers done (also guards sH if aliased)
        #pragma unroll
        for (int i = 0; i < 4; ++i) {
            float4 v;
            v.x = fmaxf(acc[i][0], 0.f); v.y = fmaxf(acc[i][1], 0.f);
            v.z = fmaxf(acc[i][2], 0.f); v.w = fmaxf(acc[i][3], 0.f);
            *reinterpret_cast<float4*>(&sH[r0 + i][tx * 4]) = v;
        }
    }
    __syncthreads();
    // stage 2: out = bf16( relu(h1 @ W2 + b2) * dinv )
    {
        float acc[4][4];
        #pragma unroll
        for (int i = 0; i < 4; ++i)
            #pragma unroll
            for (int j = 0; j < 4; ++j) acc[i][j] = sB[64 + tx * 4 + j];
        #pragma unroll 2
        for (int kb = 0; kb < 64; kb += 4) {
            float4 wv0 = *reinterpret_cast<const float4*>(&sW2[(kb + 0) * 64 + tx * 4]);
            float4 wv1 = *reinterpret_cast<const float4*>(&sW2[(kb + 1) * 64 + tx * 4]);
            float4 wv2 = *reinterpret_cast<const float4*>(&sW2[(kb + 2) * 64 + tx * 4]);
            float4 wv3 = *reinterpret_cast<const float4*>(&sW2[(kb + 3) * 64 + tx * 4]);
            #pragma unroll
            for (int i = 0; i < 4; ++i) {
                float4 xv = *reinterpret_cast<const float4*>(&sH[r0 + i][kb]);
                acc[i][0] = fmaf(xv.x, wv0.x, acc[i][0]); acc[i][1] = fmaf(xv.x, wv0.y, acc[i][1]);
                acc[i][2] = fmaf(xv.x, wv0.z, acc[i][2]); acc[i][3] = fmaf(xv.x, wv0.w, acc[i][3]);
                acc[i][0] = fmaf(xv.y, wv1.x, acc[i][0]); acc[i][1] = fmaf(xv.y, wv1.y, acc[i][1]);
                acc[i][2] = fmaf(xv.y, wv1.z, acc[i][2]); acc[i][3] = fmaf(xv.y, wv1.w, acc[i][3]);
                acc[i][0] = fmaf(xv.z, wv2.x, acc[i][0]); acc[i][1] = fmaf(xv.z, wv2.y, acc[i][1]);
                acc[i][2] = fmaf(xv.z, wv2.z, acc[i][2]); acc[i][3] = fmaf(xv.z, wv2.w, acc[i][3]);
                acc[i][0] = fmaf(xv.w, wv3.x, acc[i][0]); acc[i][1] = fmaf(xv.w, wv3.y, acc[i][1]);
                acc[i][2] = fmaf(xv.w, wv3.z, acc[i][2]); acc[i][3] = fmaf(xv.w, wv3.w, acc[i][3]);
            }
        }
        #pragma unroll
        for (int i = 0; i < 4; ++i) {
            int gn = base + r0 + i;
            if (gn >= NN) continue;
            float sc = dinv[gn];
            uint2 pv;
            pv.x = pack2bf(fmaxf(acc[i][0], 0.f) * sc, fmaxf(acc[i][1], 0.f) * sc);
            pv.y = pack2bf(fmaxf(acc[i][2], 0.f) * sc, fmaxf(acc[i][3], 0.f) * sc);
            *reinterpret_cast<uint2*>(&out[(size_t)gn * 32 + tx * 2]) = pv;
        }
    }
}

// ---------------- register-tiled dense matmul: out = (relu?)(h) @ W [+bias] [*dinv] ----------------
template <int K, int OUT, int WCOLS, bool RELU_IN, bool RELU_OUT, bool BIAS, bool OUT_BF16, bool SCALE_DINV>
__global__ __launch_bounds__(256) void mm_kernel(
    const float* __restrict__ h, int hstride,
    const float* __restrict__ w, const float* __restrict__ bias,
    const float* __restrict__ dinv,
    float* __restrict__ out, int ostride)
{
    constexpr int KC = 64;
    constexpr int NCH = K / KC;
    constexpr int NCOL = OUT / 4;
    constexpr int NROW = 256 / NCOL;
    constexpr int TM = 64 / NROW;
    __shared__ float sW[KC * OUT];
    __shared__ float sX[64][KC + 4];
    int tid = threadIdx.x;
    int tx = tid % NCOL, ty = tid / NCOL;
    int base = blockIdx.x * 64;
    int r0 = ty * TM;

    float acc[TM][4];
    #pragma unroll
    for (int i = 0; i < TM; ++i) {
        #pragma unroll
        for (int j = 0; j < 4; ++j)
            acc[i][j] = BIAS ? ((tx * 4 + j < WCOLS) ? bias[tx * 4 + j] : 0.0f) : 0.0f;
    }

    for (int ch = 0; ch < NCH; ++ch) {
        int kc = ch * KC;
        if (ch) __syncthreads();
        if constexpr (WCOLS == OUT) {
            for (int i = tid * 4; i < KC * OUT; i += 1024)
                *reinterpret_cast<float4*>(&sW[i]) =
                    *reinterpret_cast<const float4*>(&w[kc * OUT + i]);
        } else {
            for (int i = tid; i < KC * OUT; i += 256) {
                int k = i / OUT, o = i % OUT;
                sW[i] = (o < WCOLS) ? w[(kc + k) * WCOLS + o] : 0.0f;
            }
        }
        for (int i = tid * 4; i < 64 * KC; i += 1024) {
            int r = i / KC, c = i % KC;
            int gn = base + r;
            float4 v = make_float4(0.f, 0.f, 0.f, 0.f);
            if (gn < NN)
                v = *reinterpret_cast<const float4*>(&h[(size_t)gn * hstride + kc + c]);
            if (RELU_IN) {
                v.x = fmaxf(v.x, 0.f); v.y = fmaxf(v.y, 0.f);
                v.z = fmaxf(v.z, 0.f); v.w = fmaxf(v.w, 0.f);
            }
            *reinterpret_cast<float4*>(&sX[r][c]) = v;
        }
        __syncthreads();
        #pragma unroll 2
        for (int kb = 0; kb < KC; kb += 4) {
            float4 wv0 = *reinterpret_cast<const float4*>(&sW[(kb + 0) * OUT + tx * 4]);
            float4 wv1 = *reinterpret_cast<const float4*>(&sW[(kb + 1) * OUT + tx * 4]);
            float4 wv2 = *reinterpret_cast<const float4*>(&sW[(kb + 2) * OUT + tx * 4]);
            float4 wv3 = *reinterpret_cast<const float4*>(&sW[(kb + 3) * OUT + tx * 4]);
            #pragma unroll
            for (int i = 0; i < TM; ++i) {
                float4 xv = *reinterpret_cast<const float4*>(&sX[r0 + i][kb]);
                acc[i][0] = fmaf(xv.x, wv0.x, acc[i][0]); acc[i][1] = fmaf(xv.x, wv0.y, acc[i][1]);
                acc[i][2] = fmaf(xv.x, wv0.z, acc[i][2]); acc[i][3] = fmaf(xv.x, wv0.w, acc[i][3]);
                acc[i][0] = fmaf(xv.y, wv1.x, acc[i][0]); acc[i][1] = fmaf(xv.y, wv1.y, acc[i][1]);
                acc[i][2] = fmaf(xv.y, wv1.z, acc[i][2]); acc[i][3] = fmaf(xv.y, wv1.w, acc[i][3]);
                acc[i][0] = fmaf(xv.z, wv2.x, acc[i][0]); acc[i][1] = fmaf(xv.z, wv2.y, acc[i][1]);
                acc[i][2] = fmaf(xv.z, wv2.z, acc[i][2]); acc[i][3] = fmaf(xv.z, wv2.w, acc[i][3]);
                acc[i][0] = fmaf(xv.w, wv3.x, acc[i][0]); acc[i][1] = fmaf(xv.w, wv3.y, acc[i][1]);
                acc[i][2] = fmaf(xv.w, wv3.z, acc[i][2]); acc[i][3] = fmaf(xv.w, wv3.w, acc[i][3]);
            }
        }
    }

    #pragma unroll
    for (int i = 0; i < TM; ++i) {
        int gn = base + r0 + i;
        if (gn >= NN) continue;
        float4 v;
        v.x = acc[i][0]; v.y = acc[i][1]; v.z = acc[i][2]; v.w = acc[i][3];
        if (RELU_OUT) {
            v.x = fmaxf(v.x, 0.f); v.y = fmaxf(v.y, 0.f);
            v.z = fmaxf(v.z, 0.f); v.w = fmaxf(v.w, 0.f);
        }
        if constexpr (SCALE_DINV) {
            float sc = dinv[gn];
            v.x *= sc; v.y *= sc; v.z *= sc; v.w *= sc;
        }
        if constexpr (OUT_BF16) {
            unsigned* orow = reinterpret_cast<unsigned*>(out) + (size_t)gn * (ostride >> 1) + tx * 2;
            uint2 pv;
            pv.x = pack2bf(v.x, v.y);
            pv.y = pack2bf(v.z, v.w);
            *reinterpret_cast<uint2*>(orow) = pv;
        } else {
            *reinterpret_cast<float4*>(&out[(size_t)gn * ostride + tx * 4]) = v;
        }
    }
}

// ---------------- CSR gather, rows prescaled by dinv: out[n] = dinv[n]*sum(rows) ----------------
// 64 bf16 channels, 32 threads per node
__global__ __launch_bounds__(256) void gcn_gather64_bf16_kernel(
    const int* __restrict__ csr_src, const int* __restrict__ ptr, const int* __restrict__ cnt,
    const float* __restrict__ dinv, const unsigned* __restrict__ hw, float* __restrict__ out)
{
    int tid = threadIdx.x;
    int n = blockIdx.x * 8 + (tid >> 5);
    if (n >= NN) return;
    int lane = tid & 31;
    unsigned p0 = hw[(size_t)n * 32 + lane];
    float ax = __uint_as_float(p0 << 16);
    float ay = __uint_as_float(p0 & 0xffff0000u);
    int s0 = ptr[n], c = cnt[n];
    int i = 0;
    for (; i + 3 < c; i += 4) {
        unsigned pa = hw[(size_t)csr_src[s0 + i + 0] * 32 + lane];
        unsigned pb = hw[(size_t)csr_src[s0 + i + 1] * 32 + lane];
        unsigned pc = hw[(size_t)csr_src[s0 + i + 2] * 32 + lane];
        unsigned pd = hw[(size_t)csr_src[s0 + i + 3] * 32 + lane];
        ax += __uint_as_float(pa << 16);
        ay += __uint_as_float(pa & 0xffff0000u);
        ax += __uint_as_float(pb << 16);
        ay += __uint_as_float(pb & 0xffff0000u);
        ax += __uint_as_float(pc << 16);
        ay += __uint_as_float(pc & 0xffff0000u);
        ax += __uint_as_float(pd << 16);
        ay += __uint_as_float(pd & 0xffff0000u);
    }
    for (; i < c; ++i) {
        unsigned pa = hw[(size_t)csr_src[s0 + i] * 32 + lane];
        ax += __uint_as_float(pa << 16);
        ay += __uint_as_float(pa & 0xffff0000u);
    }
    float di = dinv[n];
    float2 r; r.x = ax * di; r.y = ay * di;
    *reinterpret_cast<float2*>(out + (size_t)n * 64 + lane * 2) = r;
}

// 128 bf16 channels, one wave per node, + bias
__global__ __launch_bounds__(256) void gcn_gather128_bf16_kernel(
    const int* __restrict__ csr_src, const int* __restrict__ ptr, const int* __restrict__ cnt,
    const float* __restrict__ dinv, const unsigned* __restrict__ hw, const float* __restrict__ b,
    float* __restrict__ out)
{
    int tid = threadIdx.x;
    int n = blockIdx.x * 4 + (tid >> 6);
    if (n >= NN) return;
    int lane = tid & 63;
    unsigned p0 = hw[(size_t)n * 64 + lane];
    float ax = __uint_as_float(p0 << 16);
    float ay = __uint_as_float(p0 & 0xffff0000u);
    int s0 = ptr[n], c = cnt[n];
    int i = 0;
    for (; i + 3 < c; i += 4) {
        unsigned pa = hw[(size_t)csr_src[s0 + i + 0] * 64 + lane];
        unsigned pb = hw[(size_t)csr_src[s0 + i + 1] * 64 + lane];
        unsigned pc = hw[(size_t)csr_src[s0 + i + 2] * 64 + lane];
        unsigned pd = hw[(size_t)csr_src[s0 + i + 3] * 64 + lane];
        ax += __uint_as_float(pa << 16);
        ay += __uint_as_float(pa & 0xffff0000u);
        ax += __uint_as_float(pb << 16);
        ay += __uint_as_float(pb & 0xffff0000u);
        ax += __uint_as_float(pc << 16);
        ay += __uint_as_float(pc & 0xffff0000u);
        ax += __uint_as_float(pd << 16);
        ay += __uint_as_float(pd & 0xffff0000u);
    }
    for (; i < c; ++i) {
        unsigned pa = hw[(size_t)csr_src[s0 + i] * 64 + lane];
        ax += __uint_as_float(pa << 16);
        ay += __uint_as_float(pa & 0xffff0000u);
    }
    float di = dinv[n];
    float2 bb = *reinterpret_cast<const float2*>(b + lane * 2);
    float2 r; r.x = bb.x + ax * di; r.y = bb.y + ay * di;
    *reinterpret_cast<float2*>(out + (size_t)n * 128 + lane * 2) = r;
}

// 10 fp32 channels (stride 16), 16 threads per node
__global__ void gcn_gather10_kernel(
    const int* __restrict__ csr_src, const int* __restrict__ ptr, const int* __restrict__ cnt,
    const float* __restrict__ dinv, const float* __restrict__ hw, const float* __restrict__ b,
    float* __restrict__ out)
{
    int idx = blockIdx.x * 256 + threadIdx.x;
    int n = idx >> 4;
    int ch = idx & 15;
    if (n >= NN || ch >= 10) return;
    float acc = hw[n * 16 + ch];
    int s0 = ptr[n], c = cnt[n];
    for (int i = 0; i < c; ++i)
        acc += hw[csr_src[s0 + i] * 16 + ch];
    out[n * 16 + ch] = b[ch] + acc * dinv[n];
}

// ---------------- fused segmented pool + log_softmax (batch is sorted) ----------------
__global__ __launch_bounds__(256) void pool_ls_kernel(
    const float* __restrict__ h3, const int* __restrict__ batch, float* __restrict__ out)
{
    __shared__ int seg[2];
    __shared__ float red[16][17];
    int g = blockIdx.x;
    int t = threadIdx.x;
    if (t < 2) {
        int target = g + t;
        int lo = 0, hi = NN;
        while (lo < hi) {
            int mid = (lo + hi) >> 1;
            if (batch[mid] < target) lo = mid + 1; else hi = mid;
        }
        seg[t] = lo;
    }
    __syncthreads();
    int s = seg[0], e = seg[1];
    int ch = t & 15, nl = t >> 4;
    float acc = 0.0f;
    for (int n = s + nl; n < e; n += 16)
        if (ch < 10) acc += h3[(size_t)n * 16 + ch];
    red[nl][ch] = acc;
    __syncthreads();
    if (t < 16) {
        float ssum = 0.0f;
        #pragma unroll
        for (int i = 0; i < 16; ++i) ssum += red[i][t];
        red[0][t] = ssum;
    }
    __syncthreads();
    if (t == 0) {
        float c = fmaxf((float)(e - s), 1.0f);
        float v[10], m = -1e30f;
        #pragma unroll
        for (int i = 0; i < 10; ++i) { v[i] = red[0][i] / c; m = fmaxf(m, v[i]); }
        float ssum = 0.0f;
        #pragma unroll
        for (int i = 0; i < 10; ++i) ssum += expf(v[i] - m);
        float lse = m + logf(ssum);
        #pragma unroll
        for (int i = 0; i < 10; ++i) out[g * 10 + i] = v[i] - lse;
    }
}

extern "C" void kernel_launch(void* const* d_in, const int* in_sizes, int n_in,
                              void* d_out, int out_size, void* d_ws, size_t ws_size,
                              hipStream_t stream)
{
    const float* x      = (const float*)d_in[0];
    const int*   ei     = (const int*)d_in[1];
    const int*   batch  = (const int*)d_in[2];
    const float* emb_w1 = (const float*)d_in[3];
    const float* emb_b1 = (const float*)d_in[4];
    const float* emb_w2 = (const float*)d_in[5];
    const float* emb_b2 = (const float*)d_in[6];
    const float* w1     = (const float*)d_in[7];
    const float* b1     = (const float*)d_in[8];
    const float* w2     = (const float*)d_in[9];
    const float* b2     = (const float*)d_in[10];
    const float* w3     = (const float*)d_in[11];
    const float* b3     = (const float*)d_in[12];

    int E = in_sizes[1] / 2;
    const int* src = ei;
    const int* dst = ei + E;

    // workspace layout (~55.3 MB total)
    char* ws = (char*)d_ws;
    size_t off = 0;
    float*    H1   = (float*)(ws + off);    off += (size_t)NN * 128 * 4;  // fp32 [NN,128]
    unsigned* HWB  = (unsigned*)(ws + off); off += (size_t)NN * 64 * 4;   // bf16 [NN,128]/[NN,64] ; f32 [NN,16]
    float*    A64  = (float*)(ws + off);    off += (size_t)NN * 64 * 4;   // fp32 [NN,64] ; f32 [NN,16]
    float*    dinv = (float*)(ws + off);    off += (size_t)NN * 4;
    int*      cnt  = (int*)(ws + off);      off += (size_t)NN * 4;
    int*      ptr  = (int*)(ws + off);      off += (size_t)NN * 4;
    int*      fill = (int*)(ws + off);      off += (size_t)NN * 4;
    int*      bsum = (int*)(ws + off);      off += 256 * 4;
    int*      csrs = (int*)(ws + off);      off += (size_t)E * 4;

    int mmgrid = cdiv(NN, 64);
    int egrid_part = cdiv(E, 256) * NRANGE;

    // ---- CSR build (dst-range × XCD partitioned atomics/stores) ----
    zero_int_kernel<<<cdiv(NN, 256), 256, 0, stream>>>(cnt);
    count_part_kernel<<<egrid_part, 256, 0, stream>>>(dst, cnt, E);
    scan_block_kernel<<<NBS, 256, 0, stream>>>(cnt, ptr, bsum, dinv);
    scan_tops_kernel<<<1, 256, 0, stream>>>(bsum);
    scan_add_kernel<<<NBS, 256, 0, stream>>>(ptr, fill, bsum);
    csr_fill_part_kernel<<<egrid_part, 256, 0, stream>>>(src, dst, fill, csrs, E);

    // ---- fused embedder: x -> HWB (bf16 [NN,64], prescaled by dinv) ----
    emb_fused_kernel<<<mmgrid, 256, 0, stream>>>(x, emb_w1, emb_b1, emb_w2, emb_b2, dinv, HWB);

    // ---- layer 1 reordered: aggregate 64-dim (pure sum * dinv), then matmul (+b1, relu) ----
    gcn_gather64_bf16_kernel<<<cdiv(NN, 8), 256, 0, stream>>>(csrs, ptr, cnt, dinv, HWB, A64);
    mm_kernel<64, 128, 128, false, true, true, false, false><<<mmgrid, 256, 0, stream>>>(A64, 64, w1, b1, nullptr, H1, 128);

    // ---- layer 2: matmul -> bf16 prescaled, aggregate (+b2) ----
    mm_kernel<128, 128, 128, false, false, false, true, true><<<mmgrid, 256, 0, stream>>>(H1, 128, w2, nullptr, dinv, (float*)HWB, 128);
    gcn_gather128_bf16_kernel<<<cdiv(NN, 4), 256, 0, stream>>>(csrs, ptr, cnt, dinv, HWB, b2, H1);

    // ---- layer 3: 128 -> 10 (relu_in) prescaled fp32, aggregate (+b3) ----
    mm_kernel<128, 16, 10, true, false, false, false, true><<<mmgrid, 256, 0, stream>>>(H1, 128, w3, nullptr, dinv, A64, 16);
    gcn_gather10_kernel<<<cdiv(NN * 16, 256), 256, 0, stream>>>(csrs, ptr, cnt, dinv, A64, b3, (float*)HWB);

    // ---- fused pooling + log_softmax (one block per graph) ----
    pool_ls_kernel<<<NG, 256, 0, stream>>>((float*)HWB, batch, (float*)d_out);
}

// Round 10
// 233.439 us; speedup vs baseline: 1.2821x; 1.1533x over previous
//
#include <hip/hip_runtime.h>
#include <math.h>

#define NN 50000      // nodes
#define NG 500        // graphs
#define CC 10
#define NBS 196       // cdiv(NN,256) scan blocks
#define NRANGE 8      // dst-range partitions (~XCD count)
#define RSIZE 6250    // NN / NRANGE

static inline int cdiv(int a, int b) { return (a + b - 1) / b; }

__device__ inline unsigned bf16rne(float f) {
    unsigned u = __float_as_uint(f);
    return (u + 0x7fffu + ((u >> 16) & 1u)) >> 16;
}
__device__ inline unsigned pack2bf(float a, float b) {
    return bf16rne(a) | (bf16rne(b) << 16);
}

typedef __attribute__((ext_vector_type(8))) short bf16x8;
typedef __attribute__((ext_vector_type(4))) float f32x4;

// ---------------- CSR build ----------------
__global__ void zero_int_kernel(int* __restrict__ a) {
    int i = blockIdx.x * 256 + threadIdx.x;
    if (i < NN) a[i] = 0;
}

__global__ void count_part_kernel(const int* __restrict__ dst, int* __restrict__ cnt, int nedges) {
    int r = blockIdx.x & (NRANGE - 1);
    int e = (blockIdx.x >> 3) * 256 + threadIdx.x;
    if (e >= nedges) return;
    int d = dst[e];
    if (d / RSIZE != r) return;
    atomicAdd(&cnt[d], 1);
}

__global__ void scan_block_kernel(const int* __restrict__ cnt, int* __restrict__ ptr,
                                  int* __restrict__ bsum, float* __restrict__ dinv) {
    __shared__ int s[256];
    int b = blockIdx.x, t = threadIdx.x;
    int i = b * 256 + t;
    int v = (i < NN) ? cnt[i] : 0;
    if (i < NN) dinv[i] = rsqrtf((float)v + 1.0f);  // +1 self-loop
    s[t] = v; __syncthreads();
    for (int off = 1; off < 256; off <<= 1) {
        int x = (t >= off) ? s[t - off] : 0; __syncthreads();
        s[t] += x; __syncthreads();
    }
    if (i < NN) ptr[i] = s[t] - v;
    if (t == 255) bsum[b] = s[255];
}

__global__ void scan_tops_kernel(int* __restrict__ bsum) {
    __shared__ int s[256];
    int t = threadIdx.x;
    int v = (t < NBS) ? bsum[t] : 0;
    s[t] = v; __syncthreads();
    for (int off = 1; off < 256; off <<= 1) {
        int x = (t >= off) ? s[t - off] : 0; __syncthreads();
        s[t] += x; __syncthreads();
    }
    if (t < NBS) bsum[t] = s[t] - v;
}

__global__ void scan_add_kernel(int* __restrict__ ptr, int* __restrict__ fill,
                                const int* __restrict__ bsum) {
    int i = blockIdx.x * 256 + threadIdx.x;
    if (i < NN) {
        int p = ptr[i] + bsum[blockIdx.x];
        ptr[i] = p;
        fill[i] = p;
    }
}

__global__ void csr_fill_part_kernel(const int* __restrict__ src, const int* __restrict__ dst,
                                     int* __restrict__ fill, int* __restrict__ csr_src, int nedges) {
    int r = blockIdx.x & (NRANGE - 1);
    int e = (blockIdx.x >> 3) * 256 + threadIdx.x;
    if (e >= nedges) return;
    int d = dst[e];
    if (d / RSIZE != r) return;
    int pos = atomicAdd(&fill[d], 1);
    csr_src[pos] = src[e];
}

// ---------------- weight prep: fp32 [K,OUT] -> bf16 transposed [OUT,K] ----------------
__global__ void prep_wt_kernel(const float* __restrict__ w1, const float* __restrict__ w2,
                               const float* __restrict__ w3,
                               unsigned short* __restrict__ wt1, unsigned short* __restrict__ wt2,
                               unsigned short* __restrict__ wt3) {
    int i = blockIdx.x * 256 + threadIdx.x;
    if (i < 128 * 64) {                       // wt1[o][k] = w1[k][o], K=64, OUT=128
        int o = i / 64, k = i % 64;
        wt1[i] = (unsigned short)bf16rne(w1[k * 128 + o]);
    }
    int j = i - 128 * 64;
    if (j >= 0 && j < 128 * 128) {            // wt2[o][k] = w2[k][o], K=128, OUT=128
        int o = j / 128, k = j % 128;
        wt2[j] = (unsigned short)bf16rne(w2[k * 128 + o]);
    }
    int m = j - 128 * 128;
    if (m >= 0 && m < 16 * 128) {             // wt3[o][k] = w3[k][o] (o<10), else 0
        int o = m / 128, k = m % 128;
        wt3[m] = (o < 10) ? (unsigned short)bf16rne(w3[k * 10 + o]) : 0;
    }
}

// ---------------- fused MLP embedder: x -> relu(xW1+b1) -> relu(.W2+b2)*dinv -> bf16 ----------------
__global__ __launch_bounds__(256) void emb_fused_kernel(
    const float* __restrict__ x,
    const float* __restrict__ w1, const float* __restrict__ b1,
    const float* __restrict__ w2, const float* __restrict__ b2,
    const float* __restrict__ dinv, unsigned* __restrict__ out /* bf16 [NN,64] */)
{
    __shared__ float sW1[64 * 64];
    __shared__ float sW2[64 * 64];
    __shared__ float sB[128];
    __shared__ float sX[64][68];
    __shared__ float sH[64][68];
    int tid = threadIdx.x;
    int base = blockIdx.x * 64;
    for (int i = tid * 4; i < 64 * 64; i += 1024) {
        *reinterpret_cast<float4*>(&sW1[i]) = *reinterpret_cast<const float4*>(&w1[i]);
        *reinterpret_cast<float4*>(&sW2[i]) = *reinterpret_cast<const float4*>(&w2[i]);
    }
    if (tid < 64) sB[tid] = b1[tid];
    else if (tid < 128) sB[tid] = b2[tid - 64];
    for (int i = tid * 4; i < 64 * 64; i += 1024) {
        int r = i >> 6, c = i & 63;
        int gn = base + r;
        float4 v = make_float4(0.f, 0.f, 0.f, 0.f);
        if (gn < NN) v = *reinterpret_cast<const float4*>(&x[(size_t)gn * 64 + c]);
        *reinterpret_cast<float4*>(&sX[r][c]) = v;
    }
    __syncthreads();
    int tx = tid & 15, ty = tid >> 4;
    int r0 = ty * 4;
    {
        float acc[4][4];
        #pragma unroll
        for (int i = 0; i < 4; ++i)
            #pragma unroll
            for (int j = 0; j < 4; ++j) acc[i][j] = sB[tx * 4 + j];
        #pragma unroll 2
        for (int kb = 0; kb < 64; kb += 4) {
            float4 wv0 = *reinterpret_cast<const float4*>(&sW1[(kb + 0) * 64 + tx * 4]);
            float4 wv1 = *reinterpret_cast<const float4*>(&sW1[(kb + 1) * 64 + tx * 4]);
            float4 wv2 = *reinterpret_cast<const float4*>(&sW1[(kb + 2) * 64 + tx * 4]);
            float4 wv3 = *reinterpret_cast<const float4*>(&sW1[(kb + 3) * 64 + tx * 4]);
            #pragma unroll
            for (int i = 0; i < 4; ++i) {
                float4 xv = *reinterpret_cast<const float4*>(&sX[r0 + i][kb]);
                acc[i][0] = fmaf(xv.x, wv0.x, acc[i][0]); acc[i][1] = fmaf(xv.x, wv0.y, acc[i][1]);
                acc[i][2] = fmaf(xv.x, wv0.z, acc[i][2]); acc[i][3] = fmaf(xv.x, wv0.w, acc[i][3]);
                acc[i][0] = fmaf(xv.y, wv1.x, acc[i][0]); acc[i][1] = fmaf(xv.y, wv1.y, acc[i][1]);
                acc[i][2] = fmaf(xv.y, wv1.z, acc[i][2]); acc[i][3] = fmaf(xv.y, wv1.w, acc[i][3]);
                acc[i][0] = fmaf(xv.z, wv2.x, acc[i][0]); acc[i][1] = fmaf(xv.z, wv2.y, acc[i][1]);
                acc[i][2] = fmaf(xv.z, wv2.z, acc[i][2]); acc[i][3] = fmaf(xv.z, wv2.w, acc[i][3]);
                acc[i][0] = fmaf(xv.w, wv3.x, acc[i][0]); acc[i][1] = fmaf(xv.w, wv3.y, acc[i][1]);
                acc[i][2] = fmaf(xv.w, wv3.z, acc[i][2]); acc[i][3] = fmaf(xv.w, wv3.w, acc[i][3]);
            }
        }
        __syncthreads();
        #pragma unroll
        for (int i = 0; i < 4; ++i) {
            float4 v;
            v.x = fmaxf(acc[i][0], 0.f); v.y = fmaxf(acc[i][1], 0.f);
            v.z = fmaxf(acc[i][2], 0.f); v.w = fmaxf(acc[i][3], 0.f);
            *reinterpret_cast<float4*>(&sH[r0 + i][tx * 4]) = v;
        }
    }
    __syncthreads();
    {
        float acc[4][4];
        #pragma unroll
        for (int i = 0; i < 4; ++i)
            #pragma unroll
            for (int j = 0; j < 4; ++j) acc[i][j] = sB[64 + tx * 4 + j];
        #pragma unroll 2
        for (int kb = 0; kb < 64; kb += 4) {
            float4 wv0 = *reinterpret_cast<const float4*>(&sW2[(kb + 0) * 64 + tx * 4]);
            float4 wv1 = *reinterpret_cast<const float4*>(&sW2[(kb + 1) * 64 + tx * 4]);
            float4 wv2 = *reinterpret_cast<const float4*>(&sW2[(kb + 2) * 64 + tx * 4]);
            float4 wv3 = *reinterpret_cast<const float4*>(&sW2[(kb + 3) * 64 + tx * 4]);
            #pragma unroll
            for (int i = 0; i < 4; ++i) {
                float4 xv = *reinterpret_cast<const float4*>(&sH[r0 + i][kb]);
                acc[i][0] = fmaf(xv.x, wv0.x, acc[i][0]); acc[i][1] = fmaf(xv.x, wv0.y, acc[i][1]);
                acc[i][2] = fmaf(xv.x, wv0.z, acc[i][2]); acc[i][3] = fmaf(xv.x, wv0.w, acc[i][3]);
                acc[i][0] = fmaf(xv.y, wv1.x, acc[i][0]); acc[i][1] = fmaf(xv.y, wv1.y, acc[i][1]);
                acc[i][2] = fmaf(xv.y, wv1.z, acc[i][2]); acc[i][3] = fmaf(xv.y, wv1.w, acc[i][3]);
                acc[i][0] = fmaf(xv.z, wv2.x, acc[i][0]); acc[i][1] = fmaf(xv.z, wv2.y, acc[i][1]);
                acc[i][2] = fmaf(xv.z, wv2.z, acc[i][2]); acc[i][3] = fmaf(xv.z, wv2.w, acc[i][3]);
                acc[i][0] = fmaf(xv.w, wv3.x, acc[i][0]); acc[i][1] = fmaf(xv.w, wv3.y, acc[i][1]);
                acc[i][2] = fmaf(xv.w, wv3.z, acc[i][2]); acc[i][3] = fmaf(xv.w, wv3.w, acc[i][3]);
            }
        }
        #pragma unroll
        for (int i = 0; i < 4; ++i) {
            int gn = base + r0 + i;
            if (gn >= NN) continue;
            float sc = dinv[gn];
            uint2 pv;
            pv.x = pack2bf(fmaxf(acc[i][0], 0.f) * sc, fmaxf(acc[i][1], 0.f) * sc);
            pv.y = pack2bf(fmaxf(acc[i][2], 0.f) * sc, fmaxf(acc[i][3], 0.f) * sc);
            *reinterpret_cast<uint2*>(&out[(size_t)gn * 32 + tx * 2]) = pv;
        }
    }
}

// ---------------- MFMA bf16 matmul: out = (A @ W^T_t) [+bias][relu][*dinv] ----------------
// A bf16 [NN,K]; wt bf16 [OUT,K] (pre-transposed). 64 rows/block, 4 waves x 16 rows.
// Fragments (verified m89 layout): A row=lane&15, k=(lane>>4)*8+j; B col=lane&15;
// D col=lane&15, row=(lane>>4)*4+reg.
template <int K, int OUT, bool BIAS, bool RELU_OUT, bool SCALE_DINV, bool OUT_BF16>
__global__ __launch_bounds__(256) void mfma_mm_kernel(
    const unsigned short* __restrict__ a,
    const unsigned short* __restrict__ wt,
    const float* __restrict__ bias,
    const float* __restrict__ dinv,
    void* __restrict__ outv, int ostride)
{
    constexpr int KC = 64;
    constexpr int NCH = K / KC;
    constexpr int AST = KC + 8;          // +8 bf16 pad -> 2-way-only LDS conflicts
    constexpr int NCT = OUT / 16;
    __shared__ unsigned short sA[64][AST];
    __shared__ unsigned short sW[OUT][AST];
    int tid = threadIdx.x;
    int wave = tid >> 6, lane = tid & 63;
    int base = blockIdx.x * 64;
    int r0 = wave * 16;

    f32x4 acc[NCT] = {};

    for (int ch = 0; ch < NCH; ++ch) {
        if (ch) __syncthreads();
        for (int i = tid; i < 64 * 8; i += 256) {          // KC/8 == 8 16B parts per row
            int r = i >> 3, p = i & 7;
            int gn = base + r;
            uint4 v = make_uint4(0, 0, 0, 0);
            if (gn < NN) v = *reinterpret_cast<const uint4*>(a + (size_t)gn * K + ch * KC + p * 8);
            *reinterpret_cast<uint4*>(&sA[r][p * 8]) = v;
        }
        for (int i = tid; i < OUT * 8; i += 256) {
            int o = i >> 3, p = i & 7;
            uint4 v = *reinterpret_cast<const uint4*>(wt + (size_t)o * K + ch * KC + p * 8);
            *reinterpret_cast<uint4*>(&sW[o][p * 8]) = v;
        }
        __syncthreads();
        #pragma unroll
        for (int ks = 0; ks < KC / 32; ++ks) {
            bf16x8 af = *reinterpret_cast<const bf16x8*>(&sA[r0 + (lane & 15)][ks * 32 + (lane >> 4) * 8]);
            #pragma unroll
            for (int ct = 0; ct < NCT; ++ct) {
                bf16x8 bfv = *reinterpret_cast<const bf16x8*>(&sW[ct * 16 + (lane & 15)][ks * 32 + (lane >> 4) * 8]);
                acc[ct] = __builtin_amdgcn_mfma_f32_16x16x32_bf16(af, bfv, acc[ct], 0, 0, 0);
            }
        }
    }

    int colq = lane & 15;
    int rowq = (lane >> 4) * 4;
    float dv[4];
    #pragma unroll
    for (int r = 0; r < 4; ++r) {
        int row = base + r0 + rowq + r;
        dv[r] = (SCALE_DINV && row < NN) ? dinv[row] : 1.0f;
    }
    #pragma unroll
    for (int ct = 0; ct < NCT; ++ct) {
        int col = ct * 16 + colq;
        float bv = BIAS ? bias[col] : 0.0f;
        #pragma unroll
        for (int r = 0; r < 4; ++r) {
            int row = base + r0 + rowq + r;
            if (row >= NN) continue;
            float v = acc[ct][r] + bv;
            if (RELU_OUT) v = fmaxf(v, 0.0f);
            if (SCALE_DINV) v *= dv[r];
            if (OUT_BF16)
                reinterpret_cast<unsigned short*>(outv)[(size_t)row * ostride + col] =
                    (unsigned short)bf16rne(v);
            else
                reinterpret_cast<float*>(outv)[(size_t)row * ostride + col] = v;
        }
    }
}

// ---------------- CSR gather (rows prescaled by dinv): out[n] = f(dinv[n]*sum(rows)) ----------------
// 64 bf16 channels, 32 threads/node, bf16 out
__global__ __launch_bounds__(256) void gcn_gather64_bf16_kernel(
    const int* __restrict__ csr_src, const int* __restrict__ ptr, const int* __restrict__ cnt,
    const float* __restrict__ dinv, const unsigned* __restrict__ hw, unsigned* __restrict__ out)
{
    int tid = threadIdx.x;
    int n = blockIdx.x * 8 + (tid >> 5);
    if (n >= NN) return;
    int lane = tid & 31;
    unsigned p0 = hw[(size_t)n * 32 + lane];
    float ax = __uint_as_float(p0 << 16);
    float ay = __uint_as_float(p0 & 0xffff0000u);
    int s0 = ptr[n], c = cnt[n];
    int i = 0;
    for (; i + 3 < c; i += 4) {
        unsigned pa = hw[(size_t)csr_src[s0 + i + 0] * 32 + lane];
        unsigned pb = hw[(size_t)csr_src[s0 + i + 1] * 32 + lane];
        unsigned pc = hw[(size_t)csr_src[s0 + i + 2] * 32 + lane];
        unsigned pd = hw[(size_t)csr_src[s0 + i + 3] * 32 + lane];
        ax += __uint_as_float(pa << 16); ay += __uint_as_float(pa & 0xffff0000u);
        ax += __uint_as_float(pb << 16); ay += __uint_as_float(pb & 0xffff0000u);
        ax += __uint_as_float(pc << 16); ay += __uint_as_float(pc & 0xffff0000u);
        ax += __uint_as_float(pd << 16); ay += __uint_as_float(pd & 0xffff0000u);
    }
    for (; i < c; ++i) {
        unsigned pa = hw[(size_t)csr_src[s0 + i] * 32 + lane];
        ax += __uint_as_float(pa << 16); ay += __uint_as_float(pa & 0xffff0000u);
    }
    float di = dinv[n];
    out[(size_t)n * 32 + lane] = pack2bf(ax * di, ay * di);
}

// 128 bf16 channels, one wave/node: out = relu(b + dinv*sum) -> bf16
__global__ __launch_bounds__(256) void gcn_gather128_bf16_kernel(
    const int* __restrict__ csr_src, const int* __restrict__ ptr, const int* __restrict__ cnt,
    const float* __restrict__ dinv, const unsigned* __restrict__ hw, const float* __restrict__ b,
    unsigned* __restrict__ out)
{
    int tid = threadIdx.x;
    int n = blockIdx.x * 4 + (tid >> 6);
    if (n >= NN) return;
    int lane = tid & 63;
    unsigned p0 = hw[(size_t)n * 64 + lane];
    float ax = __uint_as_float(p0 << 16);
    float ay = __uint_as_float(p0 & 0xffff0000u);
    int s0 = ptr[n], c = cnt[n];
    int i = 0;
    for (; i + 3 < c; i += 4) {
        unsigned pa = hw[(size_t)csr_src[s0 + i + 0] * 64 + lane];
        unsigned pb = hw[(size_t)csr_src[s0 + i + 1] * 64 + lane];
        unsigned pc = hw[(size_t)csr_src[s0 + i + 2] * 64 + lane];
        unsigned pd = hw[(size_t)csr_src[s0 + i + 3] * 64 + lane];
        ax += __uint_as_float(pa << 16); ay += __uint_as_float(pa & 0xffff0000u);
        ax += __uint_as_float(pb << 16); ay += __uint_as_float(pb & 0xffff0000u);
        ax += __uint_as_float(pc << 16); ay += __uint_as_float(pc & 0xffff0000u);
        ax += __uint_as_float(pd << 16); ay += __uint_as_float(pd & 0xffff0000u);
    }
    for (; i < c; ++i) {
        unsigned pa = hw[(size_t)csr_src[s0 + i] * 64 + lane];
        ax += __uint_as_float(pa << 16); ay += __uint_as_float(pa & 0xffff0000u);
    }
    float di = dinv[n];
    float2 bb = *reinterpret_cast<const float2*>(b + lane * 2);
    out[(size_t)n * 64 + lane] = pack2bf(fmaxf(bb.x + ax * di, 0.f), fmaxf(bb.y + ay * di, 0.f));
}

// 10 fp32 channels (stride 16), 16 threads/node
__global__ void gcn_gather10_kernel(
    const int* __restrict__ csr_src, const int* __restrict__ ptr, const int* __restrict__ cnt,
    const float* __restrict__ dinv, const float* __restrict__ hw, const float* __restrict__ b,
    float* __restrict__ out)
{
    int idx = blockIdx.x * 256 + threadIdx.x;
    int n = idx >> 4;
    int ch = idx & 15;
    if (n >= NN || ch >= 10) return;
    float acc = hw[n * 16 + ch];
    int s0 = ptr[n], c = cnt[n];
    for (int i = 0; i < c; ++i)
        acc += hw[csr_src[s0 + i] * 16 + ch];
    out[n * 16 + ch] = b[ch] + acc * dinv[n];
}

// ---------------- fused segmented pool + log_softmax (batch is sorted) ----------------
__global__ __launch_bounds__(256) void pool_ls_kernel(
    const float* __restrict__ h3, const int* __restrict__ batch, float* __restrict__ out)
{
    __shared__ int seg[2];
    __shared__ float red[16][17];
    int g = blockIdx.x;
    int t = threadIdx.x;
    if (t < 2) {
        int target = g + t;
        int lo = 0, hi = NN;
        while (lo < hi) {
            int mid = (lo + hi) >> 1;
            if (batch[mid] < target) lo = mid + 1; else hi = mid;
        }
        seg[t] = lo;
    }
    __syncthreads();
    int s = seg[0], e = seg[1];
    int ch = t & 15, nl = t >> 4;
    float acc = 0.0f;
    for (int n = s + nl; n < e; n += 16)
        if (ch < 10) acc += h3[(size_t)n * 16 + ch];
    red[nl][ch] = acc;
    __syncthreads();
    if (t < 16) {
        float ssum = 0.0f;
        #pragma unroll
        for (int i = 0; i < 16; ++i) ssum += red[i][t];
        red[0][t] = ssum;
    }
    __syncthreads();
    if (t == 0) {
        float c = fmaxf((float)(e - s), 1.0f);
        float v[10], m = -1e30f;
        #pragma unroll
        for (int i = 0; i < 10; ++i) { v[i] = red[0][i] / c; m = fmaxf(m, v[i]); }
        float ssum = 0.0f;
        #pragma unroll
        for (int i = 0; i < 10; ++i) ssum += expf(v[i] - m);
        float lse = m + logf(ssum);
        #pragma unroll
        for (int i = 0; i < 10; ++i) out[g * 10 + i] = v[i] - lse;
    }
}

extern "C" void kernel_launch(void* const* d_in, const int* in_sizes, int n_in,
                              void* d_out, int out_size, void* d_ws, size_t ws_size,
                              hipStream_t stream)
{
    const float* x      = (const float*)d_in[0];
    const int*   ei     = (const int*)d_in[1];
    const int*   batch  = (const int*)d_in[2];
    const float* emb_w1 = (const float*)d_in[3];
    const float* emb_b1 = (const float*)d_in[4];
    const float* emb_w2 = (const float*)d_in[5];
    const float* emb_b2 = (const float*)d_in[6];
    const float* w1     = (const float*)d_in[7];
    const float* b1     = (const float*)d_in[8];
    const float* w2     = (const float*)d_in[9];
    const float* b2     = (const float*)d_in[10];
    const float* w3     = (const float*)d_in[11];
    const float* b3     = (const float*)d_in[12];

    int E = in_sizes[1] / 2;
    const int* src = ei;
    const int* dst = ei + E;

    // workspace layout (~43 MB)
    char* ws = (char*)d_ws;
    size_t off = 0;
    unsigned short* H1b  = (unsigned short*)(ws + off); off += (size_t)NN * 128 * 2; // bf16 [NN,128]
    unsigned short* HWB  = (unsigned short*)(ws + off); off += (size_t)NN * 128 * 2; // bf16 [NN,128]
    unsigned short* EMB  = (unsigned short*)(ws + off); off += (size_t)NN * 64 * 2;  // bf16 [NN,64]; reused: M3 f32 [NN,16]
    unsigned short* A64g = (unsigned short*)(ws + off); off += (size_t)NN * 64 * 2;  // bf16 [NN,64]; reused: G10 f32 [NN,16]
    unsigned short* wt1  = (unsigned short*)(ws + off); off += 128 * 64 * 2;
    unsigned short* wt2  = (unsigned short*)(ws + off); off += 128 * 128 * 2;
    unsigned short* wt3  = (unsigned short*)(ws + off); off += 16 * 128 * 2;
    float* dinv = (float*)(ws + off); off += (size_t)NN * 4;
    int*   cnt  = (int*)(ws + off);   off += (size_t)NN * 4;
    int*   ptr  = (int*)(ws + off);   off += (size_t)NN * 4;
    int*   fill = (int*)(ws + off);   off += (size_t)NN * 4;
    int*   bsum = (int*)(ws + off);   off += 256 * 4;
    int*   csrs = (int*)(ws + off);   off += (size_t)E * 4;

    float* M3  = (float*)EMB;   // mm3 out, [NN,16] f32 (EMB consumed by then)
    float* G10 = (float*)A64g;  // gather10 out (A64g consumed by then)

    int mmgrid = cdiv(NN, 64);
    int egrid_part = cdiv(E, 256) * NRANGE;

    // ---- CSR build (dst-range x XCD partitioned) + weight prep ----
    zero_int_kernel<<<cdiv(NN, 256), 256, 0, stream>>>(cnt);
    count_part_kernel<<<egrid_part, 256, 0, stream>>>(dst, cnt, E);
    prep_wt_kernel<<<cdiv(128 * 64 + 128 * 128 + 16 * 128, 256), 256, 0, stream>>>(
        w1, w2, w3, wt1, wt2, wt3);
    scan_block_kernel<<<NBS, 256, 0, stream>>>(cnt, ptr, bsum, dinv);
    scan_tops_kernel<<<1, 256, 0, stream>>>(bsum);
    scan_add_kernel<<<NBS, 256, 0, stream>>>(ptr, fill, bsum);
    csr_fill_part_kernel<<<egrid_part, 256, 0, stream>>>(src, dst, fill, csrs, E);

    // ---- embedder: x -> EMB (bf16 [NN,64], prescaled by dinv) ----
    emb_fused_kernel<<<mmgrid, 256, 0, stream>>>(x, emb_w1, emb_b1, emb_w2, emb_b2, dinv, (unsigned*)EMB);

    // ---- layer 1: aggregate 64-dim -> bf16, MFMA matmul (+b1, relu) -> bf16 H1b ----
    gcn_gather64_bf16_kernel<<<cdiv(NN, 8), 256, 0, stream>>>(csrs, ptr, cnt, dinv, (unsigned*)EMB, (unsigned*)A64g);
    mfma_mm_kernel<64, 128, true, true, false, true><<<mmgrid, 256, 0, stream>>>(
        A64g, wt1, b1, nullptr, H1b, 128);

    // ---- layer 2: MFMA matmul *dinv -> bf16 HWB, aggregate (+b2, relu) -> bf16 H1b ----
    mfma_mm_kernel<128, 128, false, false, true, true><<<mmgrid, 256, 0, stream>>>(
        H1b, wt2, nullptr, dinv, HWB, 128);
    gcn_gather128_bf16_kernel<<<cdiv(NN, 4), 256, 0, stream>>>(csrs, ptr, cnt, dinv, (unsigned*)HWB, b2, (unsigned*)H1b);

    // ---- layer 3: MFMA matmul *dinv -> f32 M3 [NN,16], aggregate (+b3) -> f32 G10 ----
    mfma_mm_kernel<128, 16, false, false, true, false><<<mmgrid, 256, 0, stream>>>(
        H1b, wt3, nullptr, dinv, M3, 16);
    gcn_gather10_kernel<<<cdiv(NN * 16, 256), 256, 0, stream>>>(csrs, ptr, cnt, dinv, M3, b3, G10);

    // ---- fused pooling + log_softmax ----
    pool_ls_kernel<<<NG, 256, 0, stream>>>(G10, batch, (float*)d_out);
}

// Round 11
// 201.092 us; speedup vs baseline: 1.4883x; 1.1609x over previous
//
#include <hip/hip_runtime.h>
#include <math.h>

#define NN 50000      // nodes
#define NG 500        // graphs
#define CC 10
#define NBS 196       // cdiv(NN,256) scan blocks
#define NRANGE 8      // dst-range partitions (~XCD count)
#define RSIZE 6250    // NN / NRANGE

static inline int cdiv(int a, int b) { return (a + b - 1) / b; }

__device__ inline unsigned bf16rne(float f) {
    unsigned u = __float_as_uint(f);
    return (u + 0x7fffu + ((u >> 16) & 1u)) >> 16;
}
__device__ inline unsigned pack2bf(float a, float b) {
    return bf16rne(a) | (bf16rne(b) << 16);
}

typedef __attribute__((ext_vector_type(8))) short bf16x8;
typedef __attribute__((ext_vector_type(4))) float f32x4;

// ---------------- prep: zero cnt + all weight transposes (fp32 -> bf16 [OUT][K]) ----------------
__global__ void prep_all_kernel(const float* __restrict__ w1, const float* __restrict__ w2,
                                const float* __restrict__ w3,
                                const float* __restrict__ ew1, const float* __restrict__ ew2,
                                unsigned short* __restrict__ wt1, unsigned short* __restrict__ wt2,
                                unsigned short* __restrict__ wt3,
                                unsigned short* __restrict__ ewt1, unsigned short* __restrict__ ewt2,
                                int* __restrict__ cnt) {
    int i = blockIdx.x * 256 + threadIdx.x;
    if (i < NN) cnt[i] = 0;
    if (i < 128 * 64) {                        // wt1[o][k] = w1[k][o], K=64, OUT=128
        int o = i / 64, k = i % 64;
        wt1[i] = (unsigned short)bf16rne(w1[k * 128 + o]);
    }
    int j = i - 128 * 64;
    if (j >= 0 && j < 128 * 128) {             // wt2[o][k] = w2[k][o]
        int o = j / 128, k = j % 128;
        wt2[j] = (unsigned short)bf16rne(w2[k * 128 + o]);
    }
    int m = j - 128 * 128;
    if (m >= 0 && m < 16 * 128) {              // wt3[o][k] = w3[k][o] (o<10), else 0
        int o = m / 128, k = m % 128;
        wt3[m] = (o < 10) ? (unsigned short)bf16rne(w3[k * 10 + o]) : 0;
    }
    int p = m - 16 * 128;
    if (p >= 0 && p < 64 * 64) {               // ewt1[o][k] = ew1[k][o]
        int o = p / 64, k = p % 64;
        ewt1[p] = (unsigned short)bf16rne(ew1[k * 64 + o]);
    }
    int q = p - 64 * 64;
    if (q >= 0 && q < 64 * 64) {               // ewt2[o][k] = ew2[k][o]
        int o = q / 64, k = q % 64;
        ewt2[q] = (unsigned short)bf16rne(ew2[k * 64 + o]);
    }
}

// ---------------- CSR build ----------------
__global__ void count_part_kernel(const int* __restrict__ dst, int* __restrict__ cnt, int nedges) {
    int r = blockIdx.x & (NRANGE - 1);
    int e = (blockIdx.x >> 3) * 256 + threadIdx.x;
    if (e >= nedges) return;
    int d = dst[e];
    if (d / RSIZE != r) return;
    atomicAdd(&cnt[d], 1);
}

__global__ void scan_block_kernel(const int* __restrict__ cnt, int* __restrict__ ptr,
                                  int* __restrict__ bsum, float* __restrict__ dinv) {
    __shared__ int s[256];
    int b = blockIdx.x, t = threadIdx.x;
    int i = b * 256 + t;
    int v = (i < NN) ? cnt[i] : 0;
    if (i < NN) dinv[i] = rsqrtf((float)v + 1.0f);  // +1 self-loop
    s[t] = v; __syncthreads();
    for (int off = 1; off < 256; off <<= 1) {
        int x = (t >= off) ? s[t - off] : 0; __syncthreads();
        s[t] += x; __syncthreads();
    }
    if (i < NN) ptr[i] = s[t] - v;
    if (t == 255) bsum[b] = s[255];
}

__global__ void scan_tops_kernel(int* __restrict__ bsum) {
    __shared__ int s[256];
    int t = threadIdx.x;
    int v = (t < NBS) ? bsum[t] : 0;
    s[t] = v; __syncthreads();
    for (int off = 1; off < 256; off <<= 1) {
        int x = (t >= off) ? s[t - off] : 0; __syncthreads();
        s[t] += x; __syncthreads();
    }
    if (t < NBS) bsum[t] = s[t] - v;
}

__global__ void scan_add_kernel(int* __restrict__ ptr, int* __restrict__ fill,
                                const int* __restrict__ bsum) {
    int i = blockIdx.x * 256 + threadIdx.x;
    if (i < NN) {
        int p = ptr[i] + bsum[blockIdx.x];
        ptr[i] = p;
        fill[i] = p;
    }
}

__global__ void csr_fill_part_kernel(const int* __restrict__ src, const int* __restrict__ dst,
                                     int* __restrict__ fill, int* __restrict__ csr_src, int nedges) {
    int r = blockIdx.x & (NRANGE - 1);
    int e = (blockIdx.x >> 3) * 256 + threadIdx.x;
    if (e >= nedges) return;
    int d = dst[e];
    if (d / RSIZE != r) return;
    int pos = atomicAdd(&fill[d], 1);
    csr_src[pos] = src[e];
}

// ---------------- MFMA embedder: x(bf16) @ eW1 -> relu -> @ eW2 -> relu*dinv -> bf16 ----------------
__global__ __launch_bounds__(256) void emb_mfma_kernel(
    const float* __restrict__ x,
    const unsigned short* __restrict__ ewt1, const float* __restrict__ b1e,
    const unsigned short* __restrict__ ewt2, const float* __restrict__ b2e,
    const float* __restrict__ dinv, unsigned short* __restrict__ out /* bf16 [NN,64] */)
{
    constexpr int AST = 72;
    __shared__ unsigned short sX[64][AST];
    __shared__ unsigned short sW1[64][AST];
    __shared__ unsigned short sW2[64][AST];
    __shared__ unsigned short sH[64][AST];
    int tid = threadIdx.x;
    int wave = tid >> 6, lane = tid & 63;
    int base = blockIdx.x * 64;
    int r0 = wave * 16;

    for (int i = tid; i < 64 * 8; i += 256) {
        int r = i >> 3, p = i & 7;
        *reinterpret_cast<uint4*>(&sW1[r][p * 8]) =
            *reinterpret_cast<const uint4*>(ewt1 + r * 64 + p * 8);
        *reinterpret_cast<uint4*>(&sW2[r][p * 8]) =
            *reinterpret_cast<const uint4*>(ewt2 + r * 64 + p * 8);
    }
    for (int i = tid; i < 64 * 16; i += 256) {
        int r = i >> 4, p = i & 15;
        int gn = base + r;
        float4 v = make_float4(0.f, 0.f, 0.f, 0.f);
        if (gn < NN) v = *reinterpret_cast<const float4*>(&x[(size_t)gn * 64 + p * 4]);
        uint2 w; w.x = pack2bf(v.x, v.y); w.y = pack2bf(v.z, v.w);
        *reinterpret_cast<uint2*>(&sX[r][p * 4]) = w;
    }
    __syncthreads();

    int colq = lane & 15;
    int rowq = (lane >> 4) * 4;
    // stage 1: h1 = relu(x @ W1 + b1) -> sH (bf16)
    {
        f32x4 acc[4] = {};
        #pragma unroll
        for (int ks = 0; ks < 2; ++ks) {
            bf16x8 af = *reinterpret_cast<const bf16x8*>(&sX[r0 + (lane & 15)][ks * 32 + (lane >> 4) * 8]);
            #pragma unroll
            for (int ct = 0; ct < 4; ++ct) {
                bf16x8 bfv = *reinterpret_cast<const bf16x8*>(&sW1[ct * 16 + (lane & 15)][ks * 32 + (lane >> 4) * 8]);
                acc[ct] = __builtin_amdgcn_mfma_f32_16x16x32_bf16(af, bfv, acc[ct], 0, 0, 0);
            }
        }
        #pragma unroll
        for (int ct = 0; ct < 4; ++ct) {
            int col = ct * 16 + colq;
            float bv = b1e[col];
            #pragma unroll
            for (int r = 0; r < 4; ++r)
                sH[r0 + rowq + r][col] = (unsigned short)bf16rne(fmaxf(acc[ct][r] + bv, 0.f));
        }
    }
    __syncthreads();
    // stage 2: out = bf16( relu(h1 @ W2 + b2) * dinv )
    {
        f32x4 acc[4] = {};
        #pragma unroll
        for (int ks = 0; ks < 2; ++ks) {
            bf16x8 af = *reinterpret_cast<const bf16x8*>(&sH[r0 + (lane & 15)][ks * 32 + (lane >> 4) * 8]);
            #pragma unroll
            for (int ct = 0; ct < 4; ++ct) {
                bf16x8 bfv = *reinterpret_cast<const bf16x8*>(&sW2[ct * 16 + (lane & 15)][ks * 32 + (lane >> 4) * 8]);
                acc[ct] = __builtin_amdgcn_mfma_f32_16x16x32_bf16(af, bfv, acc[ct], 0, 0, 0);
            }
        }
        float dv[4];
        #pragma unroll
        for (int r = 0; r < 4; ++r) {
            int row = base + r0 + rowq + r;
            dv[r] = (row < NN) ? dinv[row] : 0.f;
        }
        #pragma unroll
        for (int ct = 0; ct < 4; ++ct) {
            int col = ct * 16 + colq;
            float bv = b2e[col];
            #pragma unroll
            for (int r = 0; r < 4; ++r) {
                int row = base + r0 + rowq + r;
                if (row >= NN) continue;
                out[(size_t)row * 64 + col] =
                    (unsigned short)bf16rne(fmaxf(acc[ct][r] + bv, 0.f) * dv[r]);
            }
        }
    }
}

// ---------------- MFMA bf16 matmul: out = (A @ W^T_t) [+bias][relu][*dinv] ----------------
template <int K, int OUT, bool BIAS, bool RELU_OUT, bool SCALE_DINV, bool OUT_BF16>
__global__ __launch_bounds__(256) void mfma_mm_kernel(
    const unsigned short* __restrict__ a,
    const unsigned short* __restrict__ wt,
    const float* __restrict__ bias,
    const float* __restrict__ dinv,
    void* __restrict__ outv, int ostride)
{
    constexpr int KC = 64;
    constexpr int NCH = K / KC;
    constexpr int AST = KC + 8;
    constexpr int NCT = OUT / 16;
    __shared__ unsigned short sA[64][AST];
    __shared__ unsigned short sW[OUT][AST];
    int tid = threadIdx.x;
    int wave = tid >> 6, lane = tid & 63;
    int base = blockIdx.x * 64;
    int r0 = wave * 16;

    f32x4 acc[NCT] = {};

    for (int ch = 0; ch < NCH; ++ch) {
        if (ch) __syncthreads();
        for (int i = tid; i < 64 * 8; i += 256) {
            int r = i >> 3, p = i & 7;
            int gn = base + r;
            uint4 v = make_uint4(0, 0, 0, 0);
            if (gn < NN) v = *reinterpret_cast<const uint4*>(a + (size_t)gn * K + ch * KC + p * 8);
            *reinterpret_cast<uint4*>(&sA[r][p * 8]) = v;
        }
        for (int i = tid; i < OUT * 8; i += 256) {
            int o = i >> 3, p = i & 7;
            uint4 v = *reinterpret_cast<const uint4*>(wt + (size_t)o * K + ch * KC + p * 8);
            *reinterpret_cast<uint4*>(&sW[o][p * 8]) = v;
        }
        __syncthreads();
        #pragma unroll
        for (int ks = 0; ks < KC / 32; ++ks) {
            bf16x8 af = *reinterpret_cast<const bf16x8*>(&sA[r0 + (lane & 15)][ks * 32 + (lane >> 4) * 8]);
            #pragma unroll
            for (int ct = 0; ct < NCT; ++ct) {
                bf16x8 bfv = *reinterpret_cast<const bf16x8*>(&sW[ct * 16 + (lane & 15)][ks * 32 + (lane >> 4) * 8]);
                acc[ct] = __builtin_amdgcn_mfma_f32_16x16x32_bf16(af, bfv, acc[ct], 0, 0, 0);
            }
        }
    }

    int colq = lane & 15;
    int rowq = (lane >> 4) * 4;
    float dv[4];
    #pragma unroll
    for (int r = 0; r < 4; ++r) {
        int row = base + r0 + rowq + r;
        dv[r] = (SCALE_DINV && row < NN) ? dinv[row] : 1.0f;
    }
    #pragma unroll
    for (int ct = 0; ct < NCT; ++ct) {
        int col = ct * 16 + colq;
        float bv = BIAS ? bias[col] : 0.0f;
        #pragma unroll
        for (int r = 0; r < 4; ++r) {
            int row = base + r0 + rowq + r;
            if (row >= NN) continue;
            float v = acc[ct][r] + bv;
            if (RELU_OUT) v = fmaxf(v, 0.0f);
            if (SCALE_DINV) v *= dv[r];
            if (OUT_BF16)
                reinterpret_cast<unsigned short*>(outv)[(size_t)row * ostride + col] =
                    (unsigned short)bf16rne(v);
            else
                reinterpret_cast<float*>(outv)[(size_t)row * ostride + col] = v;
        }
    }
}

// ---------------- CSR gather (rows prescaled by dinv), unroll 8 ----------------
#define GACC(P) ax += __uint_as_float((P) << 16); ay += __uint_as_float((P) & 0xffff0000u)

// 64 bf16 channels, 32 threads/node, bf16 out
__global__ __launch_bounds__(256) void gcn_gather64_bf16_kernel(
    const int* __restrict__ csr_src, const int* __restrict__ ptr, const int* __restrict__ cnt,
    const float* __restrict__ dinv, const unsigned* __restrict__ hw, unsigned* __restrict__ out)
{
    int tid = threadIdx.x;
    int n = blockIdx.x * 8 + (tid >> 5);
    if (n >= NN) return;
    int lane = tid & 31;
    unsigned p0 = hw[(size_t)n * 32 + lane];
    float ax = __uint_as_float(p0 << 16);
    float ay = __uint_as_float(p0 & 0xffff0000u);
    int s0 = ptr[n], c = cnt[n];
    int i = 0;
    for (; i + 7 < c; i += 8) {
        unsigned q0 = hw[(size_t)csr_src[s0 + i + 0] * 32 + lane];
        unsigned q1 = hw[(size_t)csr_src[s0 + i + 1] * 32 + lane];
        unsigned q2 = hw[(size_t)csr_src[s0 + i + 2] * 32 + lane];
        unsigned q3 = hw[(size_t)csr_src[s0 + i + 3] * 32 + lane];
        unsigned q4 = hw[(size_t)csr_src[s0 + i + 4] * 32 + lane];
        unsigned q5 = hw[(size_t)csr_src[s0 + i + 5] * 32 + lane];
        unsigned q6 = hw[(size_t)csr_src[s0 + i + 6] * 32 + lane];
        unsigned q7 = hw[(size_t)csr_src[s0 + i + 7] * 32 + lane];
        GACC(q0); GACC(q1); GACC(q2); GACC(q3);
        GACC(q4); GACC(q5); GACC(q6); GACC(q7);
    }
    for (; i + 3 < c; i += 4) {
        unsigned q0 = hw[(size_t)csr_src[s0 + i + 0] * 32 + lane];
        unsigned q1 = hw[(size_t)csr_src[s0 + i + 1] * 32 + lane];
        unsigned q2 = hw[(size_t)csr_src[s0 + i + 2] * 32 + lane];
        unsigned q3 = hw[(size_t)csr_src[s0 + i + 3] * 32 + lane];
        GACC(q0); GACC(q1); GACC(q2); GACC(q3);
    }
    for (; i < c; ++i) {
        unsigned q0 = hw[(size_t)csr_src[s0 + i] * 32 + lane];
        GACC(q0);
    }
    float di = dinv[n];
    out[(size_t)n * 32 + lane] = pack2bf(ax * di, ay * di);
}

// 128 bf16 channels, one wave/node: out = relu(b + dinv*sum) -> bf16
__global__ __launch_bounds__(256) void gcn_gather128_bf16_kernel(
    const int* __restrict__ csr_src, const int* __restrict__ ptr, const int* __restrict__ cnt,
    const float* __restrict__ dinv, const unsigned* __restrict__ hw, const float* __restrict__ b,
    unsigned* __restrict__ out)
{
    int tid = threadIdx.x;
    int n = blockIdx.x * 4 + (tid >> 6);
    if (n >= NN) return;
    int lane = tid & 63;
    unsigned p0 = hw[(size_t)n * 64 + lane];
    float ax = __uint_as_float(p0 << 16);
    float ay = __uint_as_float(p0 & 0xffff0000u);
    int s0 = ptr[n], c = cnt[n];
    int i = 0;
    for (; i + 7 < c; i += 8) {
        unsigned q0 = hw[(size_t)csr_src[s0 + i + 0] * 64 + lane];
        unsigned q1 = hw[(size_t)csr_src[s0 + i + 1] * 64 + lane];
        unsigned q2 = hw[(size_t)csr_src[s0 + i + 2] * 64 + lane];
        unsigned q3 = hw[(size_t)csr_src[s0 + i + 3] * 64 + lane];
        unsigned q4 = hw[(size_t)csr_src[s0 + i + 4] * 64 + lane];
        unsigned q5 = hw[(size_t)csr_src[s0 + i + 5] * 64 + lane];
        unsigned q6 = hw[(size_t)csr_src[s0 + i + 6] * 64 + lane];
        unsigned q7 = hw[(size_t)csr_src[s0 + i + 7] * 64 + lane];
        GACC(q0); GACC(q1); GACC(q2); GACC(q3);
        GACC(q4); GACC(q5); GACC(q6); GACC(q7);
    }
    for (; i + 3 < c; i += 4) {
        unsigned q0 = hw[(size_t)csr_src[s0 + i + 0] * 64 + lane];
        unsigned q1 = hw[(size_t)csr_src[s0 + i + 1] * 64 + lane];
        unsigned q2 = hw[(size_t)csr_src[s0 + i + 2] * 64 + lane];
        unsigned q3 = hw[(size_t)csr_src[s0 + i + 3] * 64 + lane];
        GACC(q0); GACC(q1); GACC(q2); GACC(q3);
    }
    for (; i < c; ++i) {
        unsigned q0 = hw[(size_t)csr_src[s0 + i] * 64 + lane];
        GACC(q0);
    }
    float di = dinv[n];
    float2 bb = *reinterpret_cast<const float2*>(b + lane * 2);
    out[(size_t)n * 64 + lane] = pack2bf(fmaxf(bb.x + ax * di, 0.f), fmaxf(bb.y + ay * di, 0.f));
}

// 10 fp32 channels (stride 16), 16 threads/node
__global__ void gcn_gather10_kernel(
    const int* __restrict__ csr_src, const int* __restrict__ ptr, const int* __restrict__ cnt,
    const float* __restrict__ dinv, const float* __restrict__ hw, const float* __restrict__ b,
    float* __restrict__ out)
{
    int idx = blockIdx.x * 256 + threadIdx.x;
    int n = idx >> 4;
    int ch = idx & 15;
    if (n >= NN || ch >= 10) return;
    float acc = hw[n * 16 + ch];
    int s0 = ptr[n], c = cnt[n];
    int i = 0;
    for (; i + 3 < c; i += 4) {
        float a0 = hw[csr_src[s0 + i + 0] * 16 + ch];
        float a1 = hw[csr_src[s0 + i + 1] * 16 + ch];
        float a2 = hw[csr_src[s0 + i + 2] * 16 + ch];
        float a3 = hw[csr_src[s0 + i + 3] * 16 + ch];
        acc += a0 + a1 + a2 + a3;
    }
    for (; i < c; ++i)
        acc += hw[csr_src[s0 + i] * 16 + ch];
    out[n * 16 + ch] = b[ch] + acc * dinv[n];
}

// ---------------- fused segmented pool + log_softmax (batch is sorted) ----------------
__global__ __launch_bounds__(256) void pool_ls_kernel(
    const float* __restrict__ h3, const int* __restrict__ batch, float* __restrict__ out)
{
    __shared__ int seg[2];
    __shared__ float red[16][17];
    int g = blockIdx.x;
    int t = threadIdx.x;
    if (t < 2) {
        int target = g + t;
        int lo = 0, hi = NN;
        while (lo < hi) {
            int mid = (lo + hi) >> 1;
            if (batch[mid] < target) lo = mid + 1; else hi = mid;
        }
        seg[t] = lo;
    }
    __syncthreads();
    int s = seg[0], e = seg[1];
    int ch = t & 15, nl = t >> 4;
    float acc = 0.0f;
    for (int n = s + nl; n < e; n += 16)
        if (ch < 10) acc += h3[(size_t)n * 16 + ch];
    red[nl][ch] = acc;
    __syncthreads();
    if (t < 16) {
        float ssum = 0.0f;
        #pragma unroll
        for (int i = 0; i < 16; ++i) ssum += red[i][t];
        red[0][t] = ssum;
    }
    __syncthreads();
    if (t == 0) {
        float c = fmaxf((float)(e - s), 1.0f);
        float v[10], m = -1e30f;
        #pragma unroll
        for (int i = 0; i < 10; ++i) { v[i] = red[0][i] / c; m = fmaxf(m, v[i]); }
        float ssum = 0.0f;
        #pragma unroll
        for (int i = 0; i < 10; ++i) ssum += expf(v[i] - m);
        float lse = m + logf(ssum);
        #pragma unroll
        for (int i = 0; i < 10; ++i) out[g * 10 + i] = v[i] - lse;
    }
}

extern "C" void kernel_launch(void* const* d_in, const int* in_sizes, int n_in,
                              void* d_out, int out_size, void* d_ws, size_t ws_size,
                              hipStream_t stream)
{
    const float* x      = (const float*)d_in[0];
    const int*   ei     = (const int*)d_in[1];
    const int*   batch  = (const int*)d_in[2];
    const float* emb_w1 = (const float*)d_in[3];
    const float* emb_b1 = (const float*)d_in[4];
    const float* emb_w2 = (const float*)d_in[5];
    const float* emb_b2 = (const float*)d_in[6];
    const float* w1     = (const float*)d_in[7];
    const float* b1     = (const float*)d_in[8];
    const float* w2     = (const float*)d_in[9];
    const float* b2     = (const float*)d_in[10];
    const float* w3     = (const float*)d_in[11];
    const float* b3     = (const float*)d_in[12];

    int E = in_sizes[1] / 2;
    const int* src = ei;
    const int* dst = ei + E;

    // workspace layout (~43 MB)
    char* ws = (char*)d_ws;
    size_t off = 0;
    unsigned short* H1b  = (unsigned short*)(ws + off); off += (size_t)NN * 128 * 2; // bf16 [NN,128]
    unsigned short* HWB  = (unsigned short*)(ws + off); off += (size_t)NN * 128 * 2; // bf16 [NN,128]
    unsigned short* EMB  = (unsigned short*)(ws + off); off += (size_t)NN * 64 * 2;  // bf16 [NN,64]; reused: M3 f32 [NN,16]
    unsigned short* A64g = (unsigned short*)(ws + off); off += (size_t)NN * 64 * 2;  // bf16 [NN,64]; reused: G10 f32 [NN,16]
    unsigned short* wt1  = (unsigned short*)(ws + off); off += 128 * 64 * 2;
    unsigned short* wt2  = (unsigned short*)(ws + off); off += 128 * 128 * 2;
    unsigned short* wt3  = (unsigned short*)(ws + off); off += 16 * 128 * 2;
    unsigned short* ewt1 = (unsigned short*)(ws + off); off += 64 * 64 * 2;
    unsigned short* ewt2 = (unsigned short*)(ws + off); off += 64 * 64 * 2;
    float* dinv = (float*)(ws + off); off += (size_t)NN * 4;
    int*   cnt  = (int*)(ws + off);   off += (size_t)NN * 4;
    int*   ptr  = (int*)(ws + off);   off += (size_t)NN * 4;
    int*   fill = (int*)(ws + off);   off += (size_t)NN * 4;
    int*   bsum = (int*)(ws + off);   off += 256 * 4;
    int*   csrs = (int*)(ws + off);   off += (size_t)E * 4;

    float* M3  = (float*)EMB;   // mm3 out, [NN,16] f32 (EMB consumed by then)
    float* G10 = (float*)A64g;  // gather10 out (A64g consumed by then)

    int mmgrid = cdiv(NN, 64);
    int egrid_part = cdiv(E, 256) * NRANGE;

    // ---- prep (zero cnt + weight transposes) + CSR build ----
    prep_all_kernel<<<cdiv(NN, 256), 256, 0, stream>>>(
        w1, w2, w3, emb_w1, emb_w2, wt1, wt2, wt3, ewt1, ewt2, cnt);
    count_part_kernel<<<egrid_part, 256, 0, stream>>>(dst, cnt, E);
    scan_block_kernel<<<NBS, 256, 0, stream>>>(cnt, ptr, bsum, dinv);
    scan_tops_kernel<<<1, 256, 0, stream>>>(bsum);
    scan_add_kernel<<<NBS, 256, 0, stream>>>(ptr, fill, bsum);
    csr_fill_part_kernel<<<egrid_part, 256, 0, stream>>>(src, dst, fill, csrs, E);

    // ---- embedder (MFMA): x -> EMB (bf16 [NN,64], prescaled by dinv) ----
    emb_mfma_kernel<<<mmgrid, 256, 0, stream>>>(x, ewt1, emb_b1, ewt2, emb_b2, dinv, EMB);

    // ---- layer 1: aggregate 64-dim -> bf16, MFMA matmul (+b1, relu) -> bf16 H1b ----
    gcn_gather64_bf16_kernel<<<cdiv(NN, 8), 256, 0, stream>>>(csrs, ptr, cnt, dinv, (unsigned*)EMB, (unsigned*)A64g);
    mfma_mm_kernel<64, 128, true, true, false, true><<<mmgrid, 256, 0, stream>>>(
        A64g, wt1, b1, nullptr, H1b, 128);

    // ---- layer 2: MFMA matmul *dinv -> bf16 HWB, aggregate (+b2, relu) -> bf16 H1b ----
    mfma_mm_kernel<128, 128, false, false, true, true><<<mmgrid, 256, 0, stream>>>(
        H1b, wt2, nullptr, dinv, HWB, 128);
    gcn_gather128_bf16_kernel<<<cdiv(NN, 4), 256, 0, stream>>>(csrs, ptr, cnt, dinv, (unsigned*)HWB, b2, (unsigned*)H1b);

    // ---- layer 3: MFMA matmul *dinv -> f32 M3 [NN,16], aggregate (+b3) -> f32 G10 ----
    mfma_mm_kernel<128, 16, false, false, true, false><<<mmgrid, 256, 0, stream>>>(
        H1b, wt3, nullptr, dinv, M3, 16);
    gcn_gather10_kernel<<<cdiv(NN * 16, 256), 256, 0, stream>>>(csrs, ptr, cnt, dinv, M3, b3, G10);

    // ---- fused pooling + log_softmax ----
    pool_ls_kernel<<<NG, 256, 0, stream>>>(G10, batch, (float*)d_out);
}